// Round 12
// baseline (81.540 us; speedup 1.0000x reference)
//
#include <hip/hip_runtime.h>
#include <hip/hip_bf16.h>

#define WT0 (-0.09375f)
#define WT1 (0.59375f)

// ---------------------------------------------------------------------------
// K1: 4096 blocks, two flavors, one launch.
//  lin < 2048 : level-0 loss (tile 256x4, 4 px/thread, float4 rw0). R6 body.
//  lin >= 2048: level-1 loss (tile 64x4, scalar rw1). The f1 tile (8x68 halo)
//    is rebuilt LOCALLY from fake/hdr: stage clamped 18x138 src region per
//    image SEQUENTIALLY into one buffer (keeps LDS at 14.3KB <= level-0's
//    16.6KB union -> no occupancy loss, the R7 mistake), build L1 tile, then
//    loss + write this block's f2 interior (2x32 per image) for the tail.
//    Level-1 thus has NO dependency on level-0 -> its 52MB rw1 stream
//    overlaps K1's 210MB rw0 stream instead of serializing behind it.
// No f1 materialization anywhere. NO nontemporal (R9: -40us), NO MINW (R10).
// ---------------------------------------------------------------------------
__global__ __launch_bounds__(256) void k1_kernel(
    const float* __restrict__ fake, const float* __restrict__ hdr,
    const float* __restrict__ window,
    const float* __restrict__ rw0, const float* __restrict__ rw1,
    float* __restrict__ f2, float* __restrict__ h2,
    double* __restrict__ slots)
{
    __shared__ __align__(16) float smem[4160];  // lvl0: sf2080+sh2080 | lvl1: src2484+l1F544+l1H544
    __shared__ float swin[25];
    __shared__ float wred[4];

    const int tid = threadIdx.x;
    const int tx = tid & 63, ty = tid >> 6;
    if (tid < 25) swin[tid] = window[tid];
    const int lin = blockIdx.x;
    const float wt[4] = {WT0, WT1, WT1, WT0};

    float v, scale;

    if (lin < 2048) {
        // ------------------- level-0 loss, S=512, PX=4 -------------------
        constexpr int S = 512, LW = 260;
        const int b = lin >> 8, t = lin & 255;
        const int by0 = (t >> 1) * 4, bx0 = (t & 1) * 256;
        float* sf = smem;
        float* sh = smem + 2080;
        const float* Fb = fake + (size_t)b * S * S;
        const float* Hb = hdr  + (size_t)b * S * S;
        for (int i = tid; i < 8 * LW; i += 256) {
            const int r = i / LW, c = i % LW;
            const int y = by0 + r - 2, x = bx0 + c - 2;
            float fv = 0.f, hv = 0.f;
            if ((unsigned)y < (unsigned)S && (unsigned)x < (unsigned)S) {
                const size_t id = (size_t)y * S + x;
                fv = Fb[id]; hv = Hb[id];
            }
            sf[r * LW + c] = fv; sh[r * LW + c] = hv;
        }
        __syncthreads();

        const int x0 = bx0 + 4 * tx, y = by0 + ty;
        const size_t ks = (size_t)S * S;
        const float* rwp = rw0 + (size_t)b * 25 * ks + (size_t)y * S + x0;
        float wsum[4] = {0.f,0.f,0.f,0.f}, fs[4] = {0.f,0.f,0.f,0.f}, hs[4] = {0.f,0.f,0.f,0.f};
#pragma unroll
        for (int di = 0; di < 5; ++di) {
            float f9[9], h9[9];
            const int ro = (ty + di) * LW + 4 * tx;
            const float4 a0 = *(const float4*)&sf[ro], a1 = *(const float4*)&sf[ro + 4];
            f9[0]=a0.x; f9[1]=a0.y; f9[2]=a0.z; f9[3]=a0.w;
            f9[4]=a1.x; f9[5]=a1.y; f9[6]=a1.z; f9[7]=a1.w; f9[8]=sf[ro + 8];
            const float4 b0 = *(const float4*)&sh[ro], b1 = *(const float4*)&sh[ro + 4];
            h9[0]=b0.x; h9[1]=b0.y; h9[2]=b0.z; h9[3]=b0.w;
            h9[4]=b1.x; h9[5]=b1.y; h9[6]=b1.z; h9[7]=b1.w; h9[8]=sh[ro + 8];
#pragma unroll
            for (int dj = 0; dj < 5; ++dj) {
                const int k = di * 5 + dj;
                const float4 rv = *(const float4*)(rwp + (size_t)k * ks);
                const float w0 = swin[k] * rv.x, w1 = swin[k] * rv.y;
                const float w2 = swin[k] * rv.z, w3 = swin[k] * rv.w;
                wsum[0] += w0; wsum[1] += w1; wsum[2] += w2; wsum[3] += w3;
                fs[0] = fmaf(w0, f9[dj + 0], fs[0]);
                fs[1] = fmaf(w1, f9[dj + 1], fs[1]);
                fs[2] = fmaf(w2, f9[dj + 2], fs[2]);
                fs[3] = fmaf(w3, f9[dj + 3], fs[3]);
                hs[0] = fmaf(w0, h9[dj + 0], hs[0]);
                hs[1] = fmaf(w1, h9[dj + 1], hs[1]);
                hs[2] = fmaf(w2, h9[dj + 2], hs[2]);
                hs[3] = fmaf(w3, h9[dj + 3], hs[3]);
            }
        }
        v = 0.f;
#pragma unroll
        for (int p = 0; p < 4; ++p) {
            const float d = (fs[p] - hs[p]) / wsum[p];
            v = fmaf(d, d, v);
        }
        scale = 1.0f / (8.f * 512.f * 512.f);
    } else {
        // ------- level-1 loss, S=256, tile 64x4; L1 tile from source -------
        const int p = lin - 2048;
        const int b = p >> 8, q = p & 255;
        const int bx0 = (q & 3) * 64, by0 = (q >> 2) * 4;
        float* sbuf = smem;          // [18][138] staged src (clamped)
        float* l1F  = smem + 2484;   // [8][68]
        float* l1H  = smem + 3028;   // [8][68]
        const int fr0 = 2 * by0 - 5, fc0 = 2 * bx0 - 5;

        for (int img = 0; img < 2; ++img) {
            const float* src = (img ? hdr : fake) + (size_t)b * 512 * 512;
            float* dst = img ? l1H : l1F;
            __syncthreads();                      // sbuf reuse guard
            for (int i = tid; i < 18 * 138; i += 256) {
                const int r = i / 138, c = i % 138;
                const int gy = min(max(fr0 + r, 0), 511);
                const int gx = min(max(fc0 + c, 0), 511);
                sbuf[i] = src[(size_t)gy * 512 + gx];
            }
            __syncthreads();
            // L1 local (r,c) = true f1[by0-2+r][bx0-2+c] (0 if out of image).
            // Staged slot s holds src[clamp(fr0+s)] -> tap index is 2r+ky.
            for (int i = tid; i < 8 * 68; i += 256) {
                const int r = i / 68, c = i % 68;
                const int gy1 = by0 - 2 + r, gx1 = bx0 - 2 + c;
                float a = 0.f;
                if ((unsigned)gy1 < 256u && (unsigned)gx1 < 256u) {
#pragma unroll
                    for (int ky = 0; ky < 4; ++ky) {
                        const float* row = sbuf + (2 * r + ky) * 138 + 2 * c;
                        const float rs = WT0 * (row[0] + row[3]) + WT1 * (row[1] + row[2]);
                        a = fmaf(wt[ky], rs, a);
                    }
                }
                dst[i] = a;
            }
        }
        __syncthreads();

        // write this block's f2/h2 interior (2 rows x 32 cols per image);
        // clamped taps land on in-bounds (true-value) entries of the L1 tile.
        if (tid < 128) {
            const int img = tid >> 6, j = tid & 63;
            const int r = j >> 5, c = j & 31;
            const int gy2 = (by0 >> 1) + r, gx2 = (bx0 >> 1) + c;
            const float* l1 = img ? l1H : l1F;
            int rL[4], cL[4];
#pragma unroll
            for (int k = 0; k < 4; ++k) {
                rL[k] = min(max(2 * gy2 - 1 + k, 0), 255) - (by0 - 2);
                cL[k] = min(max(2 * gx2 - 1 + k, 0), 255) - (bx0 - 2);
            }
            float a = 0.f;
#pragma unroll
            for (int ky = 0; ky < 4; ++ky) {
                const float* row = l1 + rL[ky] * 68;
                const float rs = WT0 * (row[cL[0]] + row[cL[3]])
                               + WT1 * (row[cL[1]] + row[cL[2]]);
                a = fmaf(wt[ky], rs, a);
            }
            (img ? h2 : f2)[((size_t)b * 128 + gy2) * 128 + gx2] = a;
        }

        // level-1 loss (PX=1)
        const size_t ks = 256 * 256;
        const float* rwp = rw1 + (size_t)b * 25 * ks + (size_t)(by0 + ty) * 256 + (bx0 + tx);
        float wsum = 0.f, fsv = 0.f, hsv = 0.f;
#pragma unroll
        for (int di = 0; di < 5; ++di) {
#pragma unroll
            for (int dj = 0; dj < 5; ++dj) {
                const int k = di * 5 + dj;
                const float wm = swin[k] * rwp[(size_t)k * ks];
                wsum += wm;
                fsv = fmaf(wm, l1F[(ty + di) * 68 + (tx + dj)], fsv);
                hsv = fmaf(wm, l1H[(ty + di) * 68 + (tx + dj)], hsv);
            }
        }
        const float d = (fsv - hsv) / wsum;
        v = d * d;
        scale = 0.5f / (8.f * 256.f * 256.f);
    }

#pragma unroll
    for (int off = 32; off > 0; off >>= 1) v += __shfl_down(v, off, 64);
    if ((tid & 63) == 0) wred[tid >> 6] = v;
    __syncthreads();
    if (tid == 0) {
        const float sB = wred[0] + wred[1] + wred[2] + wred[3];
        slots[lin] = (double)sB * (double)scale;
    }
}

// ---------------------------------------------------------------------------
// K2: R6's proven tail. 384 blocks: level-2 loss (256 blocks, tile 128x4,
// float2 rw2, from materialized f2) + level-3 loss (128 blocks, L3 tile
// rebuilt locally from f2 -> no global f3).
// ---------------------------------------------------------------------------
__global__ __launch_bounds__(256) void loss_tail_kernel(
    const float* __restrict__ window,
    const float* __restrict__ rw2, const float* __restrict__ rw3,
    const float* __restrict__ f2, const float* __restrict__ h2,
    double* __restrict__ slots)
{
    __shared__ float s2f[8][132];
    __shared__ float s2h[8][132];
    __shared__ float p2[2][18][128];
    __shared__ float l3[2][8][68];
    __shared__ float swin[25];
    __shared__ float wred[4];

    const int tid = threadIdx.x;
    const int tx = tid & 63, ty = tid >> 6;
    if (tid < 25) swin[tid] = window[tid];
    const int lin = blockIdx.x;

    float v = 0.f;
    float scale;

    if (lin < 256) {
        // ----- level 2: S = 128, tile 128x4, PX=2 -----
        const int b = lin >> 5, by0 = (lin & 31) * 4;
        const float* Fb = f2 + (size_t)b * 128 * 128;
        const float* Hb = h2 + (size_t)b * 128 * 128;
        for (int i = tid; i < 8 * 132; i += 256) {
            const int r = i / 132, c = i % 132;
            const int y = by0 + r - 2, x = c - 2;
            float fv = 0.f, hv = 0.f;
            if ((unsigned)y < 128u && (unsigned)x < 128u) {
                const size_t id = (size_t)y * 128 + x;
                fv = Fb[id]; hv = Hb[id];
            }
            s2f[r][c] = fv; s2h[r][c] = hv;
        }
        __syncthreads();

        const int x0 = 2 * tx, y = by0 + ty;
        const size_t ks = 128 * 128;
        const float* rwp = rw2 + (size_t)b * 25 * ks + (size_t)y * 128 + x0;
        float wsum[2] = {0.f, 0.f}, fs[2] = {0.f, 0.f}, hs[2] = {0.f, 0.f};
#pragma unroll
        for (int di = 0; di < 5; ++di) {
            float f6[6], h6[6];
            const float2* pf = (const float2*)&s2f[ty + di][2 * tx];
            const float2 a0 = pf[0], a1 = pf[1], a2 = pf[2];
            f6[0]=a0.x; f6[1]=a0.y; f6[2]=a1.x; f6[3]=a1.y; f6[4]=a2.x; f6[5]=a2.y;
            const float2* ph = (const float2*)&s2h[ty + di][2 * tx];
            const float2 b0 = ph[0], b1 = ph[1], b2 = ph[2];
            h6[0]=b0.x; h6[1]=b0.y; h6[2]=b1.x; h6[3]=b1.y; h6[4]=b2.x; h6[5]=b2.y;
#pragma unroll
            for (int dj = 0; dj < 5; ++dj) {
                const int k = di * 5 + dj;
                const float2 rv = *(const float2*)(rwp + (size_t)k * ks);
                const float w0 = swin[k] * rv.x;
                const float w1 = swin[k] * rv.y;
                wsum[0] += w0; wsum[1] += w1;
                fs[0] = fmaf(w0, f6[dj + 0], fs[0]);
                fs[1] = fmaf(w1, f6[dj + 1], fs[1]);
                hs[0] = fmaf(w0, h6[dj + 0], hs[0]);
                hs[1] = fmaf(w1, h6[dj + 1], hs[1]);
            }
        }
        const float d0 = (fs[0] - hs[0]) / wsum[0];
        const float d1 = (fs[1] - hs[1]) / wsum[1];
        v = fmaf(d0, d0, d1 * d1);
        scale = 0.25f / (8.f * 128.f * 128.f);
    } else {
        // ----- level 3: S = 64, rebuild L3 locally from f2/h2 -----
        const int t = lin - 256;
        const int b = t >> 4, by0 = (t & 15) * 4;
        const int fr0 = 2 * by0 - 5;
        for (int i = tid; i < 2 * 18 * 128; i += 256) {
            const int img = i / 2304, j = i % 2304;
            const int r = j >> 7, c = j & 127;
            const int gy = min(max(fr0 + r, 0), 127);
            p2[img][r][c] = (img ? h2 : f2)[((size_t)b * 128 + gy) * 128 + c];
        }
        __syncthreads();
        const float wt[4] = {WT0, WT1, WT1, WT0};
        for (int i = tid; i < 2 * 8 * 68; i += 256) {
            const int img = i / 544, j = i % 544;
            const int r = j / 68, c = j % 68;
            const int gy = by0 - 2 + r, gx = c - 2;
            float a = 0.f;
            if ((unsigned)gy < 64u && (unsigned)gx < 64u) {
                int ry[4], cx[4];
#pragma unroll
                for (int k = 0; k < 4; ++k) {
                    ry[k] = min(max(2 * gy - 1 + k, 0), 127) - fr0;
                    cx[k] = min(max(2 * gx - 1 + k, 0), 127);
                }
#pragma unroll
                for (int ky = 0; ky < 4; ++ky) {
                    const float* row = p2[img][ry[ky]];
                    const float rs = WT0 * (row[cx[0]] + row[cx[3]])
                                   + WT1 * (row[cx[1]] + row[cx[2]]);
                    a = fmaf(wt[ky], rs, a);
                }
            }
            l3[img][r][c] = a;
        }
        __syncthreads();

        const size_t ks = 64 * 64;
        const float* rwp = rw3 + (size_t)b * 25 * ks + (size_t)(by0 + ty) * 64 + tx;
        float wsum = 0.f, fsv = 0.f, hsv = 0.f;
#pragma unroll
        for (int di = 0; di < 5; ++di) {
#pragma unroll
            for (int dj = 0; dj < 5; ++dj) {
                const int k = di * 5 + dj;
                const float wm = swin[k] * rwp[(size_t)k * ks];
                wsum += wm;
                fsv = fmaf(wm, l3[0][ty + di][tx + dj], fsv);
                hsv = fmaf(wm, l3[1][ty + di][tx + dj], hsv);
            }
        }
        const float d = (fsv - hsv) / wsum;
        v = d * d;
        scale = 0.125f / (8.f * 64.f * 64.f);
    }

#pragma unroll
    for (int off = 32; off > 0; off >>= 1) v += __shfl_down(v, off, 64);
    if ((tid & 63) == 0) wred[tid >> 6] = v;
    __syncthreads();
    if (tid == 0) {
        const float sB = wred[0] + wred[1] + wred[2] + wred[3];
        slots[lin] = (double)sB * (double)scale;
    }
}

__global__ void finalize_kernel(const double* __restrict__ slots, float* __restrict__ out, int n)
{
    __shared__ double dred[4];
    const int t = threadIdx.x;  // 256 threads
    double s = 0.0;
    for (int i = t; i < n; i += 256) s += slots[i];
#pragma unroll
    for (int off = 32; off > 0; off >>= 1) s += __shfl_down(s, off, 64);
    if ((t & 63) == 0) dred[t >> 6] = s;
    __syncthreads();
    if (t == 0) out[0] = (float)(dred[0] + dred[1] + dred[2] + dred[3]);
}

extern "C" void kernel_launch(void* const* d_in, const int* in_sizes, int n_in,
                              void* d_out, int out_size, void* d_ws, size_t ws_size,
                              hipStream_t stream)
{
    const float* fake   = (const float*)d_in[0];
    const float* hdr    = (const float*)d_in[1];
    const float* window = (const float*)d_in[2];
    const float* rw0    = (const float*)d_in[3];
    const float* rw1    = (const float*)d_in[4];
    const float* rw2    = (const float*)d_in[5];
    const float* rw3    = (const float*)d_in[6];
    float* out = (float*)d_out;

    const int B = 8;
    char* ws = (char*)d_ws;
    double* slots = (double*)ws;                 // 4480 doubles, all stored each call
    float* f2 = (float*)(ws + 65536);
    const size_t n2 = (size_t)B * 128 * 128;
    float* h2 = f2 + n2;

    // K1: level-0 loss (2048 blk) + level-1 loss w/ local rebuild + f2 build
    // (2048 blk). One launch, no inter-flavor dependency.
    k1_kernel<<<dim3(4096), 256, 0, stream>>>(
        fake, hdr, window, rw0, rw1, f2, h2, slots);

    // K2: level-2 (256 blk) + level-3 rebuild (128 blk). slots[4096..4480).
    loss_tail_kernel<<<dim3(384), 256, 0, stream>>>(
        window, rw2, rw3, f2, h2, slots + 4096);

    // K3: final reduction of 4480 slots.
    finalize_kernel<<<1, 256, 0, stream>>>(slots, out, 4480);
}

// Round 13
// 70.318 us; speedup vs baseline: 1.1596x; 1.1596x over previous
//
#include <hip/hip_runtime.h>
#include <hip/hip_bf16.h>

#define WT0 (-0.09375f)
#define WT1 (0.59375f)

// ---------------------------------------------------------------------------
// K1: R6-exact. Level-0 loss (tile 256x4, 4 px/thread, float4 rw loads) +
// fused bicubic/2 build of f1/h1. 2048 blocks. Plain launch_bounds.
// ---------------------------------------------------------------------------
__global__ __launch_bounds__(256) void k1_kernel(
    const float* __restrict__ F0, const float* __restrict__ H0,
    const float* __restrict__ window, const float* __restrict__ RW,
    double* __restrict__ slots, float scale,
    float* __restrict__ fd, float* __restrict__ hd)
{
    constexpr int S = 512, TW = 256;
    __shared__ __align__(16) float sf[8][TW + 4];
    __shared__ __align__(16) float sh[8][TW + 4];
    __shared__ float swin[25];
    __shared__ float wred[4];

    const int tid = threadIdx.x;
    const int tx = tid & 63, ty = tid >> 6;
    if (tid < 25) swin[tid] = window[tid];

    const int bx0 = blockIdx.x * TW;
    const int by0 = blockIdx.y * 4;
    const int b   = blockIdx.z;

    const float* Fb = F0 + (size_t)b * S * S;
    const float* Hb = H0 + (size_t)b * S * S;

    for (int i = tid; i < 8 * (TW + 4); i += 256) {
        const int r = i / (TW + 4), c = i % (TW + 4);
        const int y = by0 + r - 2, x = bx0 + c - 2;
        float fv = 0.f, hv = 0.f;
        if ((unsigned)y < (unsigned)S && (unsigned)x < (unsigned)S) {
            const size_t id = (size_t)y * S + x;
            fv = Fb[id]; hv = Hb[id];
        }
        sf[r][c] = fv; sh[r][c] = hv;
    }
    __syncthreads();

    const int x0 = bx0 + 4 * tx, y = by0 + ty;
    const size_t ks = (size_t)S * S;
    const float* rwp = RW + (size_t)b * 25 * ks + (size_t)y * S + x0;

    float wsum[4] = {0.f, 0.f, 0.f, 0.f};
    float fs[4]   = {0.f, 0.f, 0.f, 0.f};
    float hs[4]   = {0.f, 0.f, 0.f, 0.f};
#pragma unroll
    for (int di = 0; di < 5; ++di) {
        float f9[9], h9[9];
        {
            const float4* pf = (const float4*)&sf[ty + di][4 * tx];
            const float4 a0 = pf[0], a1 = pf[1];
            f9[0]=a0.x; f9[1]=a0.y; f9[2]=a0.z; f9[3]=a0.w;
            f9[4]=a1.x; f9[5]=a1.y; f9[6]=a1.z; f9[7]=a1.w;
            f9[8]=sf[ty + di][4 * tx + 8];
            const float4* ph = (const float4*)&sh[ty + di][4 * tx];
            const float4 b0 = ph[0], b1 = ph[1];
            h9[0]=b0.x; h9[1]=b0.y; h9[2]=b0.z; h9[3]=b0.w;
            h9[4]=b1.x; h9[5]=b1.y; h9[6]=b1.z; h9[7]=b1.w;
            h9[8]=sh[ty + di][4 * tx + 8];
        }
#pragma unroll
        for (int dj = 0; dj < 5; ++dj) {
            const int k = di * 5 + dj;
            const float4 rv = *(const float4*)(rwp + (size_t)k * ks);
            const float w0 = swin[k] * rv.x;
            const float w1 = swin[k] * rv.y;
            const float w2 = swin[k] * rv.z;
            const float w3 = swin[k] * rv.w;
            wsum[0] += w0; wsum[1] += w1; wsum[2] += w2; wsum[3] += w3;
            fs[0] = fmaf(w0, f9[dj + 0], fs[0]);
            fs[1] = fmaf(w1, f9[dj + 1], fs[1]);
            fs[2] = fmaf(w2, f9[dj + 2], fs[2]);
            fs[3] = fmaf(w3, f9[dj + 3], fs[3]);
            hs[0] = fmaf(w0, h9[dj + 0], hs[0]);
            hs[1] = fmaf(w1, h9[dj + 1], hs[1]);
            hs[2] = fmaf(w2, h9[dj + 2], hs[2]);
            hs[3] = fmaf(w3, h9[dj + 3], hs[3]);
        }
    }
    float v = 0.f;
#pragma unroll
    for (int p = 0; p < 4; ++p) {
        const float d = (fs[p] - hs[p]) / wsum[p];
        v = fmaf(d, d, v);
    }
#pragma unroll
    for (int off = 32; off > 0; off >>= 1) v += __shfl_down(v, off, 64);
    if ((tid & 63) == 0) wred[tid >> 6] = v;

    // fused bicubic /2 from the LDS tile (edge-clamped taps)
    {
        constexpr int Sh = S / 2;
        const float wt[4] = {WT0, WT1, WT1, WT0};
        for (int i = tid; i < 512; i += 256) {
            const int img = i >> 8, t2 = i & 255;
            const int r = t2 >> 7, c = t2 & 127;
            const int g1y = (by0 >> 1) + r, g1x = (bx0 >> 1) + c;
            float (*s)[TW + 4] = img ? sh : sf;
            int lc[4];
#pragma unroll
            for (int kx = 0; kx < 4; ++kx)
                lc[kx] = min(max(bx0 + 2 * c - 1 + kx, 0), S - 1) - bx0 + 2;
            float acc = 0.f;
#pragma unroll
            for (int ky = 0; ky < 4; ++ky) {
                const int lr = min(max(by0 + 2 * r - 1 + ky, 0), S - 1) - by0 + 2;
                const float rs = WT0 * (s[lr][lc[0]] + s[lr][lc[3]])
                               + WT1 * (s[lr][lc[1]] + s[lr][lc[2]]);
                acc = fmaf(wt[ky], rs, acc);
            }
            float* dst = img ? hd : fd;
            dst[((size_t)b * Sh + g1y) * Sh + g1x] = acc;
        }
    }

    __syncthreads();
    if (tid == 0) {
        const float sB = wred[0] + wred[1] + wred[2] + wred[3];
        const unsigned lin = blockIdx.x + gridDim.x * (blockIdx.y + gridDim.y * blockIdx.z);
        slots[lin] = (double)sB * (double)scale;
    }
}

// ---------------------------------------------------------------------------
// K2: level-1 loss + fused f2/h2 build. Tile 128x4, PX=2 float2 rw loads,
// grid (2,64,8) = 1024 blocks (4/CU, 16 waves/CU — R6's 512-block PX=4
// version ran at only 4.3 TB/s: 8 waves/CU was latency-bound).
// ---------------------------------------------------------------------------
__global__ __launch_bounds__(256) void k2_kernel(
    const float* __restrict__ F0, const float* __restrict__ H0,
    const float* __restrict__ window, const float* __restrict__ RW,
    double* __restrict__ slots, float scale,
    float* __restrict__ fd, float* __restrict__ hd)
{
    constexpr int S = 256, TW = 128, LW = TW + 4;
    __shared__ __align__(16) float sf[8][LW];
    __shared__ __align__(16) float sh[8][LW];
    __shared__ float swin[25];
    __shared__ float wred[4];

    const int tid = threadIdx.x;
    const int tx = tid & 63, ty = tid >> 6;
    if (tid < 25) swin[tid] = window[tid];

    const int bx0 = blockIdx.x * TW;
    const int by0 = blockIdx.y * 4;
    const int b   = blockIdx.z;

    const float* Fb = F0 + (size_t)b * S * S;
    const float* Hb = H0 + (size_t)b * S * S;

    for (int i = tid; i < 8 * LW; i += 256) {
        const int r = i / LW, c = i % LW;
        const int y = by0 + r - 2, x = bx0 + c - 2;
        float fv = 0.f, hv = 0.f;
        if ((unsigned)y < (unsigned)S && (unsigned)x < (unsigned)S) {
            const size_t id = (size_t)y * S + x;
            fv = Fb[id]; hv = Hb[id];
        }
        sf[r][c] = fv; sh[r][c] = hv;
    }
    __syncthreads();

    const int x0 = bx0 + 2 * tx, y = by0 + ty;
    const size_t ks = (size_t)S * S;
    const float* rwp = RW + (size_t)b * 25 * ks + (size_t)y * S + x0;

    float wsum[2] = {0.f, 0.f}, fs[2] = {0.f, 0.f}, hs[2] = {0.f, 0.f};
#pragma unroll
    for (int di = 0; di < 5; ++di) {
        float f6[6], h6[6];
        const float2* pf = (const float2*)&sf[ty + di][2 * tx];
        const float2 a0 = pf[0], a1 = pf[1], a2 = pf[2];
        f6[0]=a0.x; f6[1]=a0.y; f6[2]=a1.x; f6[3]=a1.y; f6[4]=a2.x; f6[5]=a2.y;
        const float2* ph = (const float2*)&sh[ty + di][2 * tx];
        const float2 b0 = ph[0], b1 = ph[1], b2 = ph[2];
        h6[0]=b0.x; h6[1]=b0.y; h6[2]=b1.x; h6[3]=b1.y; h6[4]=b2.x; h6[5]=b2.y;
#pragma unroll
        for (int dj = 0; dj < 5; ++dj) {
            const int k = di * 5 + dj;
            const float2 rv = *(const float2*)(rwp + (size_t)k * ks);
            const float w0 = swin[k] * rv.x;
            const float w1 = swin[k] * rv.y;
            wsum[0] += w0; wsum[1] += w1;
            fs[0] = fmaf(w0, f6[dj + 0], fs[0]);
            fs[1] = fmaf(w1, f6[dj + 1], fs[1]);
            hs[0] = fmaf(w0, h6[dj + 0], hs[0]);
            hs[1] = fmaf(w1, h6[dj + 1], hs[1]);
        }
    }
    float v;
    {
        const float d0 = (fs[0] - hs[0]) / wsum[0];
        const float d1 = (fs[1] - hs[1]) / wsum[1];
        v = fmaf(d0, d0, d1 * d1);
    }
#pragma unroll
    for (int off = 32; off > 0; off >>= 1) v += __shfl_down(v, off, 64);
    if ((tid & 63) == 0) wred[tid >> 6] = v;

    // fused bicubic /2: 2 rows x 64 cols per image
    {
        constexpr int Sh = S / 2;
        const float wt[4] = {WT0, WT1, WT1, WT0};
        for (int i = tid; i < 2 * TW; i += 256) {
            const int img = i / TW, t2 = i % TW;
            const int r = t2 >> 6, c = t2 & 63;
            const int g1y = (by0 >> 1) + r, g1x = (bx0 >> 1) + c;
            float (*s)[LW] = img ? sh : sf;
            int lc[4];
#pragma unroll
            for (int kx = 0; kx < 4; ++kx)
                lc[kx] = min(max(bx0 + 2 * c - 1 + kx, 0), S - 1) - bx0 + 2;
            float acc = 0.f;
#pragma unroll
            for (int ky = 0; ky < 4; ++ky) {
                const int lr = min(max(by0 + 2 * r - 1 + ky, 0), S - 1) - by0 + 2;
                const float rs = WT0 * (s[lr][lc[0]] + s[lr][lc[3]])
                               + WT1 * (s[lr][lc[1]] + s[lr][lc[2]]);
                acc = fmaf(wt[ky], rs, acc);
            }
            float* dst = img ? hd : fd;
            dst[((size_t)b * Sh + g1y) * Sh + g1x] = acc;
        }
    }

    __syncthreads();
    if (tid == 0) {
        const float sB = wred[0] + wred[1] + wred[2] + wred[3];
        const unsigned lin = blockIdx.x + gridDim.x * (blockIdx.y + gridDim.y * blockIdx.z);
        slots[lin] = (double)sB * (double)scale;
    }
}

// ---------------------------------------------------------------------------
// K3: tail. 640 blocks: level-2 loss (512 blocks, tile 64x4 from f2, more
// blocks than R6's 256 for occupancy) + level-3 loss (128 blocks, L3 tile
// rebuilt locally from f2 — proven pattern).
// ---------------------------------------------------------------------------
__global__ __launch_bounds__(256) void loss_tail_kernel(
    const float* __restrict__ window,
    const float* __restrict__ rw2, const float* __restrict__ rw3,
    const float* __restrict__ f2, const float* __restrict__ h2,
    double* __restrict__ slots)
{
    __shared__ float smem[5696];   // lvl2: sf 544 + sh 544 | lvl3: p2 4608 + l3 1088
    __shared__ float swin[25];
    __shared__ float wred[4];

    const int tid = threadIdx.x;
    const int tx = tid & 63, ty = tid >> 6;
    if (tid < 25) swin[tid] = window[tid];
    const int lin = blockIdx.x;

    float v, scale;
    if (lin < 512) {
        // ----- level 2: S=128, tile 64x4, PX=1 -----
        constexpr int S = 128, LW = 68;
        const int b = lin >> 6, q = lin & 63;
        const int bx0 = (q & 1) * 64, by0 = (q >> 1) * 4;
        float* sf = smem;
        float* sh = smem + 544;
        const float* Fb = f2 + (size_t)b * S * S;
        const float* Hb = h2 + (size_t)b * S * S;
        for (int i = tid; i < 8 * LW; i += 256) {
            const int r = i / LW, c = i % LW;
            const int y = by0 + r - 2, x = bx0 + c - 2;
            float fv = 0.f, hv = 0.f;
            if ((unsigned)y < (unsigned)S && (unsigned)x < (unsigned)S) {
                const size_t id = (size_t)y * S + x;
                fv = Fb[id]; hv = Hb[id];
            }
            sf[r * LW + c] = fv; sh[r * LW + c] = hv;
        }
        __syncthreads();

        const size_t ks = (size_t)S * S;
        const float* rwp = rw2 + (size_t)b * 25 * ks + (size_t)(by0 + ty) * S + (bx0 + tx);
        float wsum = 0.f, fsv = 0.f, hsv = 0.f;
#pragma unroll
        for (int di = 0; di < 5; ++di) {
#pragma unroll
            for (int dj = 0; dj < 5; ++dj) {
                const int k = di * 5 + dj;
                const float wm = swin[k] * rwp[(size_t)k * ks];
                wsum += wm;
                fsv = fmaf(wm, sf[(ty + di) * LW + (tx + dj)], fsv);
                hsv = fmaf(wm, sh[(ty + di) * LW + (tx + dj)], hsv);
            }
        }
        const float d = (fsv - hsv) / wsum;
        v = d * d;
        scale = 0.25f / (8.f * 128.f * 128.f);
    } else {
        // ----- level 3: S=64, rebuild L3 locally from f2/h2 -----
        const int t = lin - 512;
        const int b = t >> 4, by0 = (t & 15) * 4;
        float* p2 = smem;          // [2][18][128]
        float* l3 = smem + 4608;   // [2][8][68]
        const int fr0 = 2 * by0 - 5;
        for (int i = tid; i < 2 * 18 * 128; i += 256) {
            const int img = i / 2304, j = i % 2304;
            const int r = j >> 7, c = j & 127;
            const int gy = min(max(fr0 + r, 0), 127);
            p2[i] = (img ? h2 : f2)[((size_t)b * 128 + gy) * 128 + c];
        }
        __syncthreads();
        const float wt[4] = {WT0, WT1, WT1, WT0};
        for (int i = tid; i < 2 * 8 * 68; i += 256) {
            const int img = i / 544, j = i % 544;
            const int r = j / 68, c = j % 68;
            const int gy = by0 - 2 + r, gx = c - 2;
            float a = 0.f;
            if ((unsigned)gy < 64u && (unsigned)gx < 64u) {
                int ry[4], cx[4];
#pragma unroll
                for (int k = 0; k < 4; ++k) {
                    ry[k] = min(max(2 * gy - 1 + k, 0), 127) - fr0;
                    cx[k] = min(max(2 * gx - 1 + k, 0), 127);
                }
#pragma unroll
                for (int ky = 0; ky < 4; ++ky) {
                    const float* row = p2 + img * 2304 + ry[ky] * 128;
                    const float rs = WT0 * (row[cx[0]] + row[cx[3]])
                                   + WT1 * (row[cx[1]] + row[cx[2]]);
                    a = fmaf(wt[ky], rs, a);
                }
            }
            l3[i] = a;
        }
        __syncthreads();

        const size_t ks = 64 * 64;
        const float* rwp = rw3 + (size_t)b * 25 * ks + (size_t)(by0 + ty) * 64 + tx;
        float wsum = 0.f, fsv = 0.f, hsv = 0.f;
#pragma unroll
        for (int di = 0; di < 5; ++di) {
#pragma unroll
            for (int dj = 0; dj < 5; ++dj) {
                const int k = di * 5 + dj;
                const float wm = swin[k] * rwp[(size_t)k * ks];
                wsum += wm;
                fsv = fmaf(wm, l3[0 * 544 + (ty + di) * 68 + (tx + dj)], fsv);
                hsv = fmaf(wm, l3[1 * 544 + (ty + di) * 68 + (tx + dj)], hsv);
            }
        }
        const float d = (fsv - hsv) / wsum;
        v = d * d;
        scale = 0.125f / (8.f * 64.f * 64.f);
    }

#pragma unroll
    for (int off = 32; off > 0; off >>= 1) v += __shfl_down(v, off, 64);
    if ((tid & 63) == 0) wred[tid >> 6] = v;
    __syncthreads();
    if (tid == 0) {
        const float sB = wred[0] + wred[1] + wred[2] + wred[3];
        slots[lin] = (double)sB * (double)scale;
    }
}

__global__ void finalize_kernel(const double* __restrict__ slots, float* __restrict__ out, int n)
{
    __shared__ double dred[4];
    const int t = threadIdx.x;  // 256 threads
    double s = 0.0;
    for (int i = t; i < n; i += 256) s += slots[i];
#pragma unroll
    for (int off = 32; off > 0; off >>= 1) s += __shfl_down(s, off, 64);
    if ((t & 63) == 0) dred[t >> 6] = s;
    __syncthreads();
    if (t == 0) out[0] = (float)(dred[0] + dred[1] + dred[2] + dred[3]);
}

extern "C" void kernel_launch(void* const* d_in, const int* in_sizes, int n_in,
                              void* d_out, int out_size, void* d_ws, size_t ws_size,
                              hipStream_t stream)
{
    const float* fake   = (const float*)d_in[0];
    const float* hdr    = (const float*)d_in[1];
    const float* window = (const float*)d_in[2];
    const float* rw0    = (const float*)d_in[3];
    const float* rw1    = (const float*)d_in[4];
    const float* rw2    = (const float*)d_in[5];
    const float* rw3    = (const float*)d_in[6];
    float* out = (float*)d_out;

    const int B = 8;
    char* ws = (char*)d_ws;
    double* slots = (double*)ws;                 // 3712 doubles, all stored each call
    float* f1 = (float*)(ws + 32768);
    const size_t n1 = (size_t)B * 256 * 256;
    float* h1 = f1 + n1;
    float* f2 = h1 + n1;
    const size_t n2 = (size_t)B * 128 * 128;
    float* h2 = f2 + n2;

    // K1: level-0 loss + f1 build. 2048 blocks (R6-exact).
    k1_kernel<<<dim3(2, 128, B), 256, 0, stream>>>(
        fake, hdr, window, rw0, slots, 1.0f / (8.f * 512.f * 512.f), f1, h1);

    // K2: level-1 loss + f2 build. 1024 blocks (tile 128x4, PX=2).
    k2_kernel<<<dim3(2, 64, B), 256, 0, stream>>>(
        f1, h1, window, rw1, slots + 2048, 0.5f / (8.f * 256.f * 256.f), f2, h2);

    // K3: level-2 (512 blk, tile 64x4) + level-3 rebuild (128 blk).
    loss_tail_kernel<<<dim3(640), 256, 0, stream>>>(
        window, rw2, rw3, f2, h2, slots + 3072);

    // K4: final reduction of 3712 slots.
    finalize_kernel<<<1, 256, 0, stream>>>(slots, out, 3712);
}

// Round 14
// 69.361 us; speedup vs baseline: 1.1756x; 1.0138x over previous
//
#include <hip/hip_runtime.h>
#include <hip/hip_bf16.h>

#define WT0 (-0.09375f)
#define WT1 (0.59375f)

// ---------------------------------------------------------------------------
// K1: level-0 loss (tile 256x8, 2 rows x 4 px per thread, float4 rw0 loads)
// + cascade build of f1 (interior 4x128/img via LDS scratch) AND f2
// (2x64/img) so the entire tail fits in ONE follow-up kernel.
// LDS: stage 2x16x264 (33.8KB, zero-padded, origin by0-4/bx0-4) + f1 scratch
// 2x6x130 (6.2KB, rows by0/2-1..+4, cols bx0/2-1..+128) = 40.2KB -> exactly
// 4 blocks/CU at 1024 blocks. No nt (R9), no MINW (R10), no foreign flavors
// (R7/R12).
// ---------------------------------------------------------------------------
__global__ __launch_bounds__(256) void k1_kernel(
    const float* __restrict__ fake, const float* __restrict__ hdr,
    const float* __restrict__ window, const float* __restrict__ RW,
    double* __restrict__ slots,
    float* __restrict__ f1, float* __restrict__ h1,
    float* __restrict__ f2, float* __restrict__ h2)
{
    __shared__ __align__(16) float stg[2][16][264];
    __shared__ float f1b[2][6][130];
    __shared__ float swin[25];
    __shared__ float wred[4];

    const int tid = threadIdx.x;
    const int tx = tid & 63, ty = tid >> 6;
    if (tid < 25) swin[tid] = window[tid];

    const int bx0 = blockIdx.x * 256;
    const int by0 = blockIdx.y * 8;
    const int b   = blockIdx.z;

    const float* Fb = fake + (size_t)b * 512 * 512;
    const float* Hb = hdr  + (size_t)b * 512 * 512;

    // stage 16x264 per image, zero-padded outside [0,512)^2
    for (int i = tid; i < 2 * 16 * 264; i += 256) {
        const int img = i / 4224, j = i % 4224;
        const int r = j / 264, c = j % 264;
        const int y = by0 - 4 + r, x = bx0 - 4 + c;
        float v = 0.f;
        if ((unsigned)y < 512u && (unsigned)x < 512u)
            v = (img ? Hb : Fb)[(size_t)y * 512 + x];
        stg[img][r][c] = v;
    }
    __syncthreads();

    // ---- loss: rows (by0+ty) and (by0+ty+4), 4 px each ----
    float vacc = 0.f;
    const size_t ks = (size_t)512 * 512;
#pragma unroll
    for (int rr = 0; rr < 2; ++rr) {
        const int y = by0 + ty + 4 * rr;
        const float* rwp = RW + (size_t)b * 25 * ks + (size_t)y * 512 + (bx0 + 4 * tx);
        float wsum[4] = {0.f,0.f,0.f,0.f}, fs[4] = {0.f,0.f,0.f,0.f}, hs[4] = {0.f,0.f,0.f,0.f};
#pragma unroll
        for (int di = 0; di < 5; ++di) {
            const int srow = ty + 4 * rr + di + 2;     // image row y+di-2
            float f12[12], h12[12];
            {   // aligned 3x float4: stage cols [4tx, 4tx+12) = image cols bx0+4tx-4..+7
                const float4* pf = (const float4*)&stg[0][srow][4 * tx];
                const float4 a0 = pf[0], a1 = pf[1], a2 = pf[2];
                f12[0]=a0.x; f12[1]=a0.y; f12[2]=a0.z;  f12[3]=a0.w;
                f12[4]=a1.x; f12[5]=a1.y; f12[6]=a1.z;  f12[7]=a1.w;
                f12[8]=a2.x; f12[9]=a2.y; f12[10]=a2.z; f12[11]=a2.w;
                const float4* ph = (const float4*)&stg[1][srow][4 * tx];
                const float4 b0 = ph[0], b1 = ph[1], b2 = ph[2];
                h12[0]=b0.x; h12[1]=b0.y; h12[2]=b0.z;  h12[3]=b0.w;
                h12[4]=b1.x; h12[5]=b1.y; h12[6]=b1.z;  h12[7]=b1.w;
                h12[8]=b2.x; h12[9]=b2.y; h12[10]=b2.z; h12[11]=b2.w;
            }
#pragma unroll
            for (int dj = 0; dj < 5; ++dj) {
                const int k = di * 5 + dj;
                const float4 rv = *(const float4*)(rwp + (size_t)k * ks);
                const float w0 = swin[k] * rv.x, w1 = swin[k] * rv.y;
                const float w2 = swin[k] * rv.z, w3 = swin[k] * rv.w;
                wsum[0] += w0; wsum[1] += w1; wsum[2] += w2; wsum[3] += w3;
                fs[0] = fmaf(w0, f12[dj + 2], fs[0]);
                fs[1] = fmaf(w1, f12[dj + 3], fs[1]);
                fs[2] = fmaf(w2, f12[dj + 4], fs[2]);
                fs[3] = fmaf(w3, f12[dj + 5], fs[3]);
                hs[0] = fmaf(w0, h12[dj + 2], hs[0]);
                hs[1] = fmaf(w1, h12[dj + 3], hs[1]);
                hs[2] = fmaf(w2, h12[dj + 4], hs[2]);
                hs[3] = fmaf(w3, h12[dj + 5], hs[3]);
            }
        }
#pragma unroll
        for (int p = 0; p < 4; ++p) {
            const float d = (fs[p] - hs[p]) / wsum[p];
            vacc = fmaf(d, d, vacc);
        }
    }
#pragma unroll
    for (int off = 32; off > 0; off >>= 1) vacc += __shfl_down(vacc, off, 64);
    if ((tid & 63) == 0) wred[tid >> 6] = vacc;

    // ---- f1 build: rows by0/2-1..+4, cols bx0/2-1..+128 (clamped taps on
    // stage -> always true pixels); interior 4x128 written to global ----
    const float wt[4] = {WT0, WT1, WT1, WT0};
    for (int i = tid; i < 2 * 6 * 130; i += 256) {
        const int img = i / 780, j = i % 780;
        const int rr = j / 130, cc = j % 130;
        const int r1 = (by0 >> 1) - 1 + rr;
        const int c1 = (bx0 >> 1) - 1 + cc;
        int sy[4], sx[4];
#pragma unroll
        for (int k = 0; k < 4; ++k) {
            sy[k] = min(max(2 * r1 - 1 + k, 0), 511) - (by0 - 4);
            sx[k] = min(max(2 * c1 - 1 + k, 0), 511) - (bx0 - 4);
        }
        float a = 0.f;
#pragma unroll
        for (int ky = 0; ky < 4; ++ky) {
            const float* row = stg[img][sy[ky]];
            const float rs = WT0 * (row[sx[0]] + row[sx[3]])
                           + WT1 * (row[sx[1]] + row[sx[2]]);
            a = fmaf(wt[ky], rs, a);
        }
        f1b[img][rr][cc] = a;
        if (rr >= 1 && rr < 5 && cc >= 1 && cc < 129)
            (img ? h1 : f1)[(size_t)b * 65536 + (size_t)r1 * 256 + c1] = a;
    }
    __syncthreads();

    // ---- f2 build: 2 img x 2 rows x 64 cols = 256 values (1/thread),
    // clamped taps on the f1 scratch ----
    {
        const int img = tid >> 7, j = tid & 127;
        const int rr2 = j >> 6, cc2 = j & 63;
        const int y2 = (by0 >> 2) + rr2;
        const int x2 = (bx0 >> 2) + cc2;
        int fr[4], fc[4];
#pragma unroll
        for (int k = 0; k < 4; ++k) {
            fr[k] = min(max(2 * y2 - 1 + k, 0), 255) - ((by0 >> 1) - 1);
            fc[k] = min(max(2 * x2 - 1 + k, 0), 255) - ((bx0 >> 1) - 1);
        }
        float a = 0.f;
#pragma unroll
        for (int ky = 0; ky < 4; ++ky) {
            const float* row = f1b[img][fr[ky]];
            const float rs = WT0 * (row[fc[0]] + row[fc[3]])
                           + WT1 * (row[fc[1]] + row[fc[2]]);
            a = fmaf(wt[ky], rs, a);
        }
        (img ? h2 : f2)[(size_t)b * 16384 + (size_t)y2 * 128 + x2] = a;
    }

    if (tid == 0) {
        const float sB = wred[0] + wred[1] + wred[2] + wred[3];
        const unsigned lin = blockIdx.x + 2u * (blockIdx.y + 64u * blockIdx.z);
        slots[lin] = (double)sB * (double)(1.0f / (8.f * 512.f * 512.f));
    }
}

// ---------------------------------------------------------------------------
// K_B: the ENTIRE tail in one launch (896 blocks). All flavors only read
// f1/f2 (materialized by K1) -> no intra-kernel dependencies, all rw streams
// concurrent. lin<512: level-1 (tile 256x4, PX=4). 512..767: level-2 (tile
// 128x4, PX=2). 768..895: level-3 (L3 rebuilt locally from f2, proven body).
// ---------------------------------------------------------------------------
__global__ __launch_bounds__(256) void kb_kernel(
    const float* __restrict__ window,
    const float* __restrict__ rw1, const float* __restrict__ rw2,
    const float* __restrict__ rw3,
    const float* __restrict__ f1, const float* __restrict__ h1,
    const float* __restrict__ f2, const float* __restrict__ h2,
    double* __restrict__ slots)
{
    __shared__ __align__(16) float smem[5696]; // lvl1 4160 | lvl2 2112 | lvl3 5696
    __shared__ float swin[25];
    __shared__ float wred[4];

    const int tid = threadIdx.x;
    const int tx = tid & 63, ty = tid >> 6;
    if (tid < 25) swin[tid] = window[tid];
    const int lin = blockIdx.x;

    float v, scale;
    if (lin < 512) {
        // ---- level-1: S=256, tile 256x4, PX=4, float4 rw1 ----
        constexpr int S = 256, LW = 260;
        const int b = lin >> 6, by0 = (lin & 63) * 4;
        float* sf = smem;
        float* sh = smem + 2080;
        const float* Fb = f1 + (size_t)b * S * S;
        const float* Hb = h1 + (size_t)b * S * S;
        for (int i = tid; i < 8 * LW; i += 256) {
            const int r = i / LW, c = i % LW;
            const int y = by0 + r - 2, x = c - 2;
            float fv = 0.f, hv = 0.f;
            if ((unsigned)y < (unsigned)S && (unsigned)x < (unsigned)S) {
                const size_t id = (size_t)y * S + x;
                fv = Fb[id]; hv = Hb[id];
            }
            sf[r * LW + c] = fv; sh[r * LW + c] = hv;
        }
        __syncthreads();

        const size_t ks = (size_t)S * S;
        const float* rwp = rw1 + (size_t)b * 25 * ks + (size_t)(by0 + ty) * S + 4 * tx;
        float wsum[4] = {0.f,0.f,0.f,0.f}, fs[4] = {0.f,0.f,0.f,0.f}, hs[4] = {0.f,0.f,0.f,0.f};
#pragma unroll
        for (int di = 0; di < 5; ++di) {
            float f9[9], h9[9];
            const int ro = (ty + di) * LW + 4 * tx;
            const float4 a0 = *(const float4*)&sf[ro], a1 = *(const float4*)&sf[ro + 4];
            f9[0]=a0.x; f9[1]=a0.y; f9[2]=a0.z; f9[3]=a0.w;
            f9[4]=a1.x; f9[5]=a1.y; f9[6]=a1.z; f9[7]=a1.w; f9[8]=sf[ro + 8];
            const float4 b0 = *(const float4*)&sh[ro], b1 = *(const float4*)&sh[ro + 4];
            h9[0]=b0.x; h9[1]=b0.y; h9[2]=b0.z; h9[3]=b0.w;
            h9[4]=b1.x; h9[5]=b1.y; h9[6]=b1.z; h9[7]=b1.w; h9[8]=sh[ro + 8];
#pragma unroll
            for (int dj = 0; dj < 5; ++dj) {
                const int k = di * 5 + dj;
                const float4 rv = *(const float4*)(rwp + (size_t)k * ks);
                const float w0 = swin[k] * rv.x, w1 = swin[k] * rv.y;
                const float w2 = swin[k] * rv.z, w3 = swin[k] * rv.w;
                wsum[0] += w0; wsum[1] += w1; wsum[2] += w2; wsum[3] += w3;
                fs[0] = fmaf(w0, f9[dj + 0], fs[0]);
                fs[1] = fmaf(w1, f9[dj + 1], fs[1]);
                fs[2] = fmaf(w2, f9[dj + 2], fs[2]);
                fs[3] = fmaf(w3, f9[dj + 3], fs[3]);
                hs[0] = fmaf(w0, h9[dj + 0], hs[0]);
                hs[1] = fmaf(w1, h9[dj + 1], hs[1]);
                hs[2] = fmaf(w2, h9[dj + 2], hs[2]);
                hs[3] = fmaf(w3, h9[dj + 3], hs[3]);
            }
        }
        v = 0.f;
#pragma unroll
        for (int p = 0; p < 4; ++p) {
            const float d = (fs[p] - hs[p]) / wsum[p];
            v = fmaf(d, d, v);
        }
        scale = 0.5f / (8.f * 256.f * 256.f);
    } else if (lin < 768) {
        // ---- level-2: S=128, tile 128x4, PX=2, float2 rw2 ----
        constexpr int S = 128, LW = 132;
        const int t = lin - 512;
        const int b = t >> 5, by0 = (t & 31) * 4;
        float* sf = smem;
        float* sh = smem + 1056;
        const float* Fb = f2 + (size_t)b * S * S;
        const float* Hb = h2 + (size_t)b * S * S;
        for (int i = tid; i < 8 * LW; i += 256) {
            const int r = i / LW, c = i % LW;
            const int y = by0 + r - 2, x = c - 2;
            float fv = 0.f, hv = 0.f;
            if ((unsigned)y < (unsigned)S && (unsigned)x < (unsigned)S) {
                const size_t id = (size_t)y * S + x;
                fv = Fb[id]; hv = Hb[id];
            }
            sf[r * LW + c] = fv; sh[r * LW + c] = hv;
        }
        __syncthreads();

        const size_t ks = (size_t)S * S;
        const float* rwp = rw2 + (size_t)b * 25 * ks + (size_t)(by0 + ty) * S + 2 * tx;
        float wsum[2] = {0.f,0.f}, fs[2] = {0.f,0.f}, hs[2] = {0.f,0.f};
#pragma unroll
        for (int di = 0; di < 5; ++di) {
            float f6[6], h6[6];
            const int ro = (ty + di) * LW + 2 * tx;
            const float2 a0 = *(const float2*)&sf[ro], a1 = *(const float2*)&sf[ro + 2],
                         a2 = *(const float2*)&sf[ro + 4];
            f6[0]=a0.x; f6[1]=a0.y; f6[2]=a1.x; f6[3]=a1.y; f6[4]=a2.x; f6[5]=a2.y;
            const float2 b0 = *(const float2*)&sh[ro], b1 = *(const float2*)&sh[ro + 2],
                         b2 = *(const float2*)&sh[ro + 4];
            h6[0]=b0.x; h6[1]=b0.y; h6[2]=b1.x; h6[3]=b1.y; h6[4]=b2.x; h6[5]=b2.y;
#pragma unroll
            for (int dj = 0; dj < 5; ++dj) {
                const int k = di * 5 + dj;
                const float2 rv = *(const float2*)(rwp + (size_t)k * ks);
                const float w0 = swin[k] * rv.x, w1 = swin[k] * rv.y;
                wsum[0] += w0; wsum[1] += w1;
                fs[0] = fmaf(w0, f6[dj + 0], fs[0]);
                fs[1] = fmaf(w1, f6[dj + 1], fs[1]);
                hs[0] = fmaf(w0, h6[dj + 0], hs[0]);
                hs[1] = fmaf(w1, h6[dj + 1], hs[1]);
            }
        }
        const float d0 = (fs[0] - hs[0]) / wsum[0];
        const float d1 = (fs[1] - hs[1]) / wsum[1];
        v = fmaf(d0, d0, d1 * d1);
        scale = 0.25f / (8.f * 128.f * 128.f);
    } else {
        // ---- level-3: S=64, rebuild L3 tile locally from f2/h2 ----
        const int t = lin - 768;
        const int b = t >> 4, by0 = (t & 15) * 4;
        float* p2 = smem;          // [2][18][128]
        float* l3 = smem + 4608;   // [2][8][68]
        const int fr0 = 2 * by0 - 5;
        for (int i = tid; i < 2 * 18 * 128; i += 256) {
            const int img = i / 2304, j = i % 2304;
            const int r = j >> 7, c = j & 127;
            const int gy = min(max(fr0 + r, 0), 127);
            p2[i] = (img ? h2 : f2)[((size_t)b * 128 + gy) * 128 + c];
        }
        __syncthreads();
        const float wt[4] = {WT0, WT1, WT1, WT0};
        for (int i = tid; i < 2 * 8 * 68; i += 256) {
            const int img = i / 544, j = i % 544;
            const int r = j / 68, c = j % 68;
            const int gy = by0 - 2 + r, gx = c - 2;
            float a = 0.f;
            if ((unsigned)gy < 64u && (unsigned)gx < 64u) {
                int ry[4], cx[4];
#pragma unroll
                for (int k = 0; k < 4; ++k) {
                    ry[k] = min(max(2 * gy - 1 + k, 0), 127) - fr0;
                    cx[k] = min(max(2 * gx - 1 + k, 0), 127);
                }
#pragma unroll
                for (int ky = 0; ky < 4; ++ky) {
                    const float* row = p2 + img * 2304 + ry[ky] * 128;
                    const float rs = WT0 * (row[cx[0]] + row[cx[3]])
                                   + WT1 * (row[cx[1]] + row[cx[2]]);
                    a = fmaf(wt[ky], rs, a);
                }
            }
            l3[i] = a;
        }
        __syncthreads();

        const size_t ks = 64 * 64;
        const float* rwp = rw3 + (size_t)b * 25 * ks + (size_t)(by0 + ty) * 64 + tx;
        float wsum = 0.f, fsv = 0.f, hsv = 0.f;
#pragma unroll
        for (int di = 0; di < 5; ++di) {
#pragma unroll
            for (int dj = 0; dj < 5; ++dj) {
                const int k = di * 5 + dj;
                const float wm = swin[k] * rwp[(size_t)k * ks];
                wsum += wm;
                fsv = fmaf(wm, l3[0 * 544 + (ty + di) * 68 + (tx + dj)], fsv);
                hsv = fmaf(wm, l3[1 * 544 + (ty + di) * 68 + (tx + dj)], hsv);
            }
        }
        const float d = (fsv - hsv) / wsum;
        v = d * d;
        scale = 0.125f / (8.f * 64.f * 64.f);
    }

#pragma unroll
    for (int off = 32; off > 0; off >>= 1) v += __shfl_down(v, off, 64);
    if ((tid & 63) == 0) wred[tid >> 6] = v;
    __syncthreads();
    if (tid == 0) {
        const float sB = wred[0] + wred[1] + wred[2] + wred[3];
        slots[lin] = (double)sB * (double)scale;
    }
}

__global__ void finalize_kernel(const double* __restrict__ slots, float* __restrict__ out, int n)
{
    __shared__ double dred[4];
    const int t = threadIdx.x;  // 256 threads
    double s = 0.0;
    for (int i = t; i < n; i += 256) s += slots[i];
#pragma unroll
    for (int off = 32; off > 0; off >>= 1) s += __shfl_down(s, off, 64);
    if ((t & 63) == 0) dred[t >> 6] = s;
    __syncthreads();
    if (t == 0) out[0] = (float)(dred[0] + dred[1] + dred[2] + dred[3]);
}

extern "C" void kernel_launch(void* const* d_in, const int* in_sizes, int n_in,
                              void* d_out, int out_size, void* d_ws, size_t ws_size,
                              hipStream_t stream)
{
    const float* fake   = (const float*)d_in[0];
    const float* hdr    = (const float*)d_in[1];
    const float* window = (const float*)d_in[2];
    const float* rw0    = (const float*)d_in[3];
    const float* rw1    = (const float*)d_in[4];
    const float* rw2    = (const float*)d_in[5];
    const float* rw3    = (const float*)d_in[6];
    float* out = (float*)d_out;

    const int B = 8;
    char* ws = (char*)d_ws;
    double* slots = (double*)ws;                 // 1920 doubles, all stored each call
    float* f1 = (float*)(ws + 32768);
    const size_t n1 = (size_t)B * 256 * 256;
    float* h1 = f1 + n1;
    float* f2 = h1 + n1;
    const size_t n2 = (size_t)B * 128 * 128;
    float* h2 = f2 + n2;

    // K1: level-0 loss + f1 + f2 build. 1024 blocks (4/CU, 40KB LDS).
    k1_kernel<<<dim3(2, 64, B), 256, 0, stream>>>(
        fake, hdr, window, rw0, slots, f1, h1, f2, h2);

    // K_B: levels 1+2+3 in one launch (512+256+128 = 896 blocks).
    kb_kernel<<<dim3(896), 256, 0, stream>>>(
        window, rw1, rw2, rw3, f1, h1, f2, h2, slots + 1024);

    // finalize: 1920 slots.
    finalize_kernel<<<1, 256, 0, stream>>>(slots, out, 1920);
}

// Round 15
// 63.508 us; speedup vs baseline: 1.2839x; 1.0922x over previous
//
#include <hip/hip_runtime.h>
#include <hip/hip_bf16.h>

#define WT0 (-0.09375f)
#define WT1 (0.59375f)

// ---------------------------------------------------------------------------
// K1: level-0 loss (tile 256x8, 2 rows x 4 px per thread, float4 rw0 loads)
// + cascade build of f1 AND f2 (R14 structure, best known). This round's
// single change: staging is float4-vectorized — since bx0 % 4 == 0 and the
// halo offset is -4, every 16B quad is fully in- or out-of-bounds, so the
// zero-pad predicate applies per-quad (9 vector loads/thread vs 33 scalar).
// ---------------------------------------------------------------------------
__global__ __launch_bounds__(256) void k1_kernel(
    const float* __restrict__ fake, const float* __restrict__ hdr,
    const float* __restrict__ window, const float* __restrict__ RW,
    double* __restrict__ slots,
    float* __restrict__ f1, float* __restrict__ h1,
    float* __restrict__ f2, float* __restrict__ h2)
{
    __shared__ __align__(16) float stg[2][16][264];
    __shared__ float f1b[2][6][130];
    __shared__ float swin[25];
    __shared__ float wred[4];

    const int tid = threadIdx.x;
    const int tx = tid & 63, ty = tid >> 6;
    if (tid < 25) swin[tid] = window[tid];

    const int bx0 = blockIdx.x * 256;
    const int by0 = blockIdx.y * 8;
    const int b   = blockIdx.z;

    const float* Fb = fake + (size_t)b * 512 * 512;
    const float* Hb = hdr  + (size_t)b * 512 * 512;

    // stage 16x264 per image as float4 quads (264 = 66 quads/row), zero-pad
    // outside [0,512)^2. xs multiple of 4 -> (unsigned)xs<512 == quad fully in.
    for (int i = tid; i < 2 * 16 * 66; i += 256) {
        const int img = i / 1056, j = i % 1056;
        const int r = j / 66, c4 = j % 66;
        const int y = by0 - 4 + r, xs = bx0 - 4 + 4 * c4;
        float4 v = make_float4(0.f, 0.f, 0.f, 0.f);
        if ((unsigned)y < 512u && (unsigned)xs < 512u)
            v = *(const float4*)((img ? Hb : Fb) + (size_t)y * 512 + xs);
        *(float4*)&stg[img][r][4 * c4] = v;
    }
    __syncthreads();

    // ---- loss: rows (by0+ty) and (by0+ty+4), 4 px each ----
    float vacc = 0.f;
    const size_t ks = (size_t)512 * 512;
#pragma unroll
    for (int rr = 0; rr < 2; ++rr) {
        const int y = by0 + ty + 4 * rr;
        const float* rwp = RW + (size_t)b * 25 * ks + (size_t)y * 512 + (bx0 + 4 * tx);
        float wsum[4] = {0.f,0.f,0.f,0.f}, fs[4] = {0.f,0.f,0.f,0.f}, hs[4] = {0.f,0.f,0.f,0.f};
#pragma unroll
        for (int di = 0; di < 5; ++di) {
            const int srow = ty + 4 * rr + di + 2;     // image row y+di-2
            float f12[12], h12[12];
            {   // aligned 3x float4: stage cols [4tx, 4tx+12) = image cols bx0+4tx-4..+7
                const float4* pf = (const float4*)&stg[0][srow][4 * tx];
                const float4 a0 = pf[0], a1 = pf[1], a2 = pf[2];
                f12[0]=a0.x; f12[1]=a0.y; f12[2]=a0.z;  f12[3]=a0.w;
                f12[4]=a1.x; f12[5]=a1.y; f12[6]=a1.z;  f12[7]=a1.w;
                f12[8]=a2.x; f12[9]=a2.y; f12[10]=a2.z; f12[11]=a2.w;
                const float4* ph = (const float4*)&stg[1][srow][4 * tx];
                const float4 b0 = ph[0], b1 = ph[1], b2 = ph[2];
                h12[0]=b0.x; h12[1]=b0.y; h12[2]=b0.z;  h12[3]=b0.w;
                h12[4]=b1.x; h12[5]=b1.y; h12[6]=b1.z;  h12[7]=b1.w;
                h12[8]=b2.x; h12[9]=b2.y; h12[10]=b2.z; h12[11]=b2.w;
            }
#pragma unroll
            for (int dj = 0; dj < 5; ++dj) {
                const int k = di * 5 + dj;
                const float4 rv = *(const float4*)(rwp + (size_t)k * ks);
                const float w0 = swin[k] * rv.x, w1 = swin[k] * rv.y;
                const float w2 = swin[k] * rv.z, w3 = swin[k] * rv.w;
                wsum[0] += w0; wsum[1] += w1; wsum[2] += w2; wsum[3] += w3;
                fs[0] = fmaf(w0, f12[dj + 2], fs[0]);
                fs[1] = fmaf(w1, f12[dj + 3], fs[1]);
                fs[2] = fmaf(w2, f12[dj + 4], fs[2]);
                fs[3] = fmaf(w3, f12[dj + 5], fs[3]);
                hs[0] = fmaf(w0, h12[dj + 2], hs[0]);
                hs[1] = fmaf(w1, h12[dj + 3], hs[1]);
                hs[2] = fmaf(w2, h12[dj + 4], hs[2]);
                hs[3] = fmaf(w3, h12[dj + 5], hs[3]);
            }
        }
#pragma unroll
        for (int p = 0; p < 4; ++p) {
            const float d = (fs[p] - hs[p]) / wsum[p];
            vacc = fmaf(d, d, vacc);
        }
    }
#pragma unroll
    for (int off = 32; off > 0; off >>= 1) vacc += __shfl_down(vacc, off, 64);
    if ((tid & 63) == 0) wred[tid >> 6] = vacc;

    // ---- f1 build: rows by0/2-1..+4, cols bx0/2-1..+128 (clamped taps on
    // stage -> always true pixels); interior 4x128 written to global ----
    const float wt[4] = {WT0, WT1, WT1, WT0};
    for (int i = tid; i < 2 * 6 * 130; i += 256) {
        const int img = i / 780, j = i % 780;
        const int rr = j / 130, cc = j % 130;
        const int r1 = (by0 >> 1) - 1 + rr;
        const int c1 = (bx0 >> 1) - 1 + cc;
        int sy[4], sx[4];
#pragma unroll
        for (int k = 0; k < 4; ++k) {
            sy[k] = min(max(2 * r1 - 1 + k, 0), 511) - (by0 - 4);
            sx[k] = min(max(2 * c1 - 1 + k, 0), 511) - (bx0 - 4);
        }
        float a = 0.f;
#pragma unroll
        for (int ky = 0; ky < 4; ++ky) {
            const float* row = stg[img][sy[ky]];
            const float rs = WT0 * (row[sx[0]] + row[sx[3]])
                           + WT1 * (row[sx[1]] + row[sx[2]]);
            a = fmaf(wt[ky], rs, a);
        }
        f1b[img][rr][cc] = a;
        if (rr >= 1 && rr < 5 && cc >= 1 && cc < 129)
            (img ? h1 : f1)[(size_t)b * 65536 + (size_t)r1 * 256 + c1] = a;
    }
    __syncthreads();

    // ---- f2 build: 2 img x 2 rows x 64 cols = 256 values (1/thread),
    // clamped taps on the f1 scratch ----
    {
        const int img = tid >> 7, j = tid & 127;
        const int rr2 = j >> 6, cc2 = j & 63;
        const int y2 = (by0 >> 2) + rr2;
        const int x2 = (bx0 >> 2) + cc2;
        int fr[4], fc[4];
#pragma unroll
        for (int k = 0; k < 4; ++k) {
            fr[k] = min(max(2 * y2 - 1 + k, 0), 255) - ((by0 >> 1) - 1);
            fc[k] = min(max(2 * x2 - 1 + k, 0), 255) - ((bx0 >> 1) - 1);
        }
        float a = 0.f;
#pragma unroll
        for (int ky = 0; ky < 4; ++ky) {
            const float* row = f1b[img][fr[ky]];
            const float rs = WT0 * (row[fc[0]] + row[fc[3]])
                           + WT1 * (row[fc[1]] + row[fc[2]]);
            a = fmaf(wt[ky], rs, a);
        }
        (img ? h2 : f2)[(size_t)b * 16384 + (size_t)y2 * 128 + x2] = a;
    }

    if (tid == 0) {
        const float sB = wred[0] + wred[1] + wred[2] + wred[3];
        const unsigned lin = blockIdx.x + 2u * (blockIdx.y + 64u * blockIdx.z);
        slots[lin] = (double)sB * (double)(1.0f / (8.f * 512.f * 512.f));
    }
}

// ---------------------------------------------------------------------------
// K_B: the ENTIRE tail in one launch (896 blocks). All flavors only read
// f1/f2 (materialized by K1) -> no intra-kernel dependencies, all rw streams
// concurrent. lin<512: level-1 (tile 256x4, PX=4). 512..767: level-2 (tile
// 128x4, PX=2). 768..895: level-3 (L3 rebuilt locally from f2, proven body).
// ---------------------------------------------------------------------------
__global__ __launch_bounds__(256) void kb_kernel(
    const float* __restrict__ window,
    const float* __restrict__ rw1, const float* __restrict__ rw2,
    const float* __restrict__ rw3,
    const float* __restrict__ f1, const float* __restrict__ h1,
    const float* __restrict__ f2, const float* __restrict__ h2,
    double* __restrict__ slots)
{
    __shared__ __align__(16) float smem[5696]; // lvl1 4160 | lvl2 2112 | lvl3 5696
    __shared__ float swin[25];
    __shared__ float wred[4];

    const int tid = threadIdx.x;
    const int tx = tid & 63, ty = tid >> 6;
    if (tid < 25) swin[tid] = window[tid];
    const int lin = blockIdx.x;

    float v, scale;
    if (lin < 512) {
        // ---- level-1: S=256, tile 256x4, PX=4, float4 rw1 ----
        constexpr int S = 256, LW = 260;
        const int b = lin >> 6, by0 = (lin & 63) * 4;
        float* sf = smem;
        float* sh = smem + 2080;
        const float* Fb = f1 + (size_t)b * S * S;
        const float* Hb = h1 + (size_t)b * S * S;
        for (int i = tid; i < 8 * LW; i += 256) {
            const int r = i / LW, c = i % LW;
            const int y = by0 + r - 2, x = c - 2;
            float fv = 0.f, hv = 0.f;
            if ((unsigned)y < (unsigned)S && (unsigned)x < (unsigned)S) {
                const size_t id = (size_t)y * S + x;
                fv = Fb[id]; hv = Hb[id];
            }
            sf[r * LW + c] = fv; sh[r * LW + c] = hv;
        }
        __syncthreads();

        const size_t ks = (size_t)S * S;
        const float* rwp = rw1 + (size_t)b * 25 * ks + (size_t)(by0 + ty) * S + 4 * tx;
        float wsum[4] = {0.f,0.f,0.f,0.f}, fs[4] = {0.f,0.f,0.f,0.f}, hs[4] = {0.f,0.f,0.f,0.f};
#pragma unroll
        for (int di = 0; di < 5; ++di) {
            float f9[9], h9[9];
            const int ro = (ty + di) * LW + 4 * tx;
            const float4 a0 = *(const float4*)&sf[ro], a1 = *(const float4*)&sf[ro + 4];
            f9[0]=a0.x; f9[1]=a0.y; f9[2]=a0.z; f9[3]=a0.w;
            f9[4]=a1.x; f9[5]=a1.y; f9[6]=a1.z; f9[7]=a1.w; f9[8]=sf[ro + 8];
            const float4 b0 = *(const float4*)&sh[ro], b1 = *(const float4*)&sh[ro + 4];
            h9[0]=b0.x; h9[1]=b0.y; h9[2]=b0.z; h9[3]=b0.w;
            h9[4]=b1.x; h9[5]=b1.y; h9[6]=b1.z; h9[7]=b1.w; h9[8]=sh[ro + 8];
#pragma unroll
            for (int dj = 0; dj < 5; ++dj) {
                const int k = di * 5 + dj;
                const float4 rv = *(const float4*)(rwp + (size_t)k * ks);
                const float w0 = swin[k] * rv.x, w1 = swin[k] * rv.y;
                const float w2 = swin[k] * rv.z, w3 = swin[k] * rv.w;
                wsum[0] += w0; wsum[1] += w1; wsum[2] += w2; wsum[3] += w3;
                fs[0] = fmaf(w0, f9[dj + 0], fs[0]);
                fs[1] = fmaf(w1, f9[dj + 1], fs[1]);
                fs[2] = fmaf(w2, f9[dj + 2], fs[2]);
                fs[3] = fmaf(w3, f9[dj + 3], fs[3]);
                hs[0] = fmaf(w0, h9[dj + 0], hs[0]);
                hs[1] = fmaf(w1, h9[dj + 1], hs[1]);
                hs[2] = fmaf(w2, h9[dj + 2], hs[2]);
                hs[3] = fmaf(w3, h9[dj + 3], hs[3]);
            }
        }
        v = 0.f;
#pragma unroll
        for (int p = 0; p < 4; ++p) {
            const float d = (fs[p] - hs[p]) / wsum[p];
            v = fmaf(d, d, v);
        }
        scale = 0.5f / (8.f * 256.f * 256.f);
    } else if (lin < 768) {
        // ---- level-2: S=128, tile 128x4, PX=2, float2 rw2 ----
        constexpr int S = 128, LW = 132;
        const int t = lin - 512;
        const int b = t >> 5, by0 = (t & 31) * 4;
        float* sf = smem;
        float* sh = smem + 1056;
        const float* Fb = f2 + (size_t)b * S * S;
        const float* Hb = h2 + (size_t)b * S * S;
        for (int i = tid; i < 8 * LW; i += 256) {
            const int r = i / LW, c = i % LW;
            const int y = by0 + r - 2, x = c - 2;
            float fv = 0.f, hv = 0.f;
            if ((unsigned)y < (unsigned)S && (unsigned)x < (unsigned)S) {
                const size_t id = (size_t)y * S + x;
                fv = Fb[id]; hv = Hb[id];
            }
            sf[r * LW + c] = fv; sh[r * LW + c] = hv;
        }
        __syncthreads();

        const size_t ks = (size_t)S * S;
        const float* rwp = rw2 + (size_t)b * 25 * ks + (size_t)(by0 + ty) * S + 2 * tx;
        float wsum[2] = {0.f,0.f}, fs[2] = {0.f,0.f}, hs[2] = {0.f,0.f};
#pragma unroll
        for (int di = 0; di < 5; ++di) {
            float f6[6], h6[6];
            const int ro = (ty + di) * LW + 2 * tx;
            const float2 a0 = *(const float2*)&sf[ro], a1 = *(const float2*)&sf[ro + 2],
                         a2 = *(const float2*)&sf[ro + 4];
            f6[0]=a0.x; f6[1]=a0.y; f6[2]=a1.x; f6[3]=a1.y; f6[4]=a2.x; f6[5]=a2.y;
            const float2 b0 = *(const float2*)&sh[ro], b1 = *(const float2*)&sh[ro + 2],
                         b2 = *(const float2*)&sh[ro + 4];
            h6[0]=b0.x; h6[1]=b0.y; h6[2]=b1.x; h6[3]=b1.y; h6[4]=b2.x; h6[5]=b2.y;
#pragma unroll
            for (int dj = 0; dj < 5; ++dj) {
                const int k = di * 5 + dj;
                const float2 rv = *(const float2*)(rwp + (size_t)k * ks);
                const float w0 = swin[k] * rv.x, w1 = swin[k] * rv.y;
                wsum[0] += w0; wsum[1] += w1;
                fs[0] = fmaf(w0, f6[dj + 0], fs[0]);
                fs[1] = fmaf(w1, f6[dj + 1], fs[1]);
                hs[0] = fmaf(w0, h6[dj + 0], hs[0]);
                hs[1] = fmaf(w1, h6[dj + 1], hs[1]);
            }
        }
        const float d0 = (fs[0] - hs[0]) / wsum[0];
        const float d1 = (fs[1] - hs[1]) / wsum[1];
        v = fmaf(d0, d0, d1 * d1);
        scale = 0.25f / (8.f * 128.f * 128.f);
    } else {
        // ---- level-3: S=64, rebuild L3 tile locally from f2/h2 ----
        const int t = lin - 768;
        const int b = t >> 4, by0 = (t & 15) * 4;
        float* p2 = smem;          // [2][18][128]
        float* l3 = smem + 4608;   // [2][8][68]
        const int fr0 = 2 * by0 - 5;
        for (int i = tid; i < 2 * 18 * 128; i += 256) {
            const int img = i / 2304, j = i % 2304;
            const int r = j >> 7, c = j & 127;
            const int gy = min(max(fr0 + r, 0), 127);
            p2[i] = (img ? h2 : f2)[((size_t)b * 128 + gy) * 128 + c];
        }
        __syncthreads();
        const float wt[4] = {WT0, WT1, WT1, WT0};
        for (int i = tid; i < 2 * 8 * 68; i += 256) {
            const int img = i / 544, j = i % 544;
            const int r = j / 68, c = j % 68;
            const int gy = by0 - 2 + r, gx = c - 2;
            float a = 0.f;
            if ((unsigned)gy < 64u && (unsigned)gx < 64u) {
                int ry[4], cx[4];
#pragma unroll
                for (int k = 0; k < 4; ++k) {
                    ry[k] = min(max(2 * gy - 1 + k, 0), 127) - fr0;
                    cx[k] = min(max(2 * gx - 1 + k, 0), 127);
                }
#pragma unroll
                for (int ky = 0; ky < 4; ++ky) {
                    const float* row = p2 + img * 2304 + ry[ky] * 128;
                    const float rs = WT0 * (row[cx[0]] + row[cx[3]])
                                   + WT1 * (row[cx[1]] + row[cx[2]]);
                    a = fmaf(wt[ky], rs, a);
                }
            }
            l3[i] = a;
        }
        __syncthreads();

        const size_t ks = 64 * 64;
        const float* rwp = rw3 + (size_t)b * 25 * ks + (size_t)(by0 + ty) * 64 + tx;
        float wsum = 0.f, fsv = 0.f, hsv = 0.f;
#pragma unroll
        for (int di = 0; di < 5; ++di) {
#pragma unroll
            for (int dj = 0; dj < 5; ++dj) {
                const int k = di * 5 + dj;
                const float wm = swin[k] * rwp[(size_t)k * ks];
                wsum += wm;
                fsv = fmaf(wm, l3[0 * 544 + (ty + di) * 68 + (tx + dj)], fsv);
                hsv = fmaf(wm, l3[1 * 544 + (ty + di) * 68 + (tx + dj)], hsv);
            }
        }
        const float d = (fsv - hsv) / wsum;
        v = d * d;
        scale = 0.125f / (8.f * 64.f * 64.f);
    }

#pragma unroll
    for (int off = 32; off > 0; off >>= 1) v += __shfl_down(v, off, 64);
    if ((tid & 63) == 0) wred[tid >> 6] = v;
    __syncthreads();
    if (tid == 0) {
        const float sB = wred[0] + wred[1] + wred[2] + wred[3];
        slots[lin] = (double)sB * (double)scale;
    }
}

__global__ void finalize_kernel(const double* __restrict__ slots, float* __restrict__ out, int n)
{
    __shared__ double dred[4];
    const int t = threadIdx.x;  // 256 threads
    double s = 0.0;
    for (int i = t; i < n; i += 256) s += slots[i];
#pragma unroll
    for (int off = 32; off > 0; off >>= 1) s += __shfl_down(s, off, 64);
    if ((t & 63) == 0) dred[t >> 6] = s;
    __syncthreads();
    if (t == 0) out[0] = (float)(dred[0] + dred[1] + dred[2] + dred[3]);
}

extern "C" void kernel_launch(void* const* d_in, const int* in_sizes, int n_in,
                              void* d_out, int out_size, void* d_ws, size_t ws_size,
                              hipStream_t stream)
{
    const float* fake   = (const float*)d_in[0];
    const float* hdr    = (const float*)d_in[1];
    const float* window = (const float*)d_in[2];
    const float* rw0    = (const float*)d_in[3];
    const float* rw1    = (const float*)d_in[4];
    const float* rw2    = (const float*)d_in[5];
    const float* rw3    = (const float*)d_in[6];
    float* out = (float*)d_out;

    const int B = 8;
    char* ws = (char*)d_ws;
    double* slots = (double*)ws;                 // 1920 doubles, all stored each call
    float* f1 = (float*)(ws + 32768);
    const size_t n1 = (size_t)B * 256 * 256;
    float* h1 = f1 + n1;
    float* f2 = h1 + n1;
    const size_t n2 = (size_t)B * 128 * 128;
    float* h2 = f2 + n2;

    // K1: level-0 loss + f1 + f2 build. 1024 blocks (4/CU, 40KB LDS).
    k1_kernel<<<dim3(2, 64, B), 256, 0, stream>>>(
        fake, hdr, window, rw0, slots, f1, h1, f2, h2);

    // K_B: levels 1+2+3 in one launch (512+256+128 = 896 blocks).
    kb_kernel<<<dim3(896), 256, 0, stream>>>(
        window, rw1, rw2, rw3, f1, h1, f2, h2, slots + 1024);

    // finalize: 1920 slots.
    finalize_kernel<<<1, 256, 0, stream>>>(slots, out, 1920);
}

// Round 16
// 61.462 us; speedup vs baseline: 1.3267x; 1.0333x over previous
//
#include <hip/hip_runtime.h>
#include <hip/hip_bf16.h>

#define WT0 (-0.09375f)
#define WT1 (0.59375f)

// ---------------------------------------------------------------------------
// K1: R15-exact (best known). Level-0 loss (tile 256x8, 2 rows x 4 px/thread,
// float4 rw0 loads) + cascade f1 + f2 build. float4 quad staging.
// ---------------------------------------------------------------------------
__global__ __launch_bounds__(256) void k1_kernel(
    const float* __restrict__ fake, const float* __restrict__ hdr,
    const float* __restrict__ window, const float* __restrict__ RW,
    double* __restrict__ slots,
    float* __restrict__ f1, float* __restrict__ h1,
    float* __restrict__ f2, float* __restrict__ h2)
{
    __shared__ __align__(16) float stg[2][16][264];
    __shared__ float f1b[2][6][130];
    __shared__ float swin[25];
    __shared__ float wred[4];

    const int tid = threadIdx.x;
    const int tx = tid & 63, ty = tid >> 6;
    if (tid < 25) swin[tid] = window[tid];

    const int bx0 = blockIdx.x * 256;
    const int by0 = blockIdx.y * 8;
    const int b   = blockIdx.z;

    const float* Fb = fake + (size_t)b * 512 * 512;
    const float* Hb = hdr  + (size_t)b * 512 * 512;

    // stage 16x264 per image as float4 quads, zero-pad outside [0,512)^2
    for (int i = tid; i < 2 * 16 * 66; i += 256) {
        const int img = i / 1056, j = i % 1056;
        const int r = j / 66, c4 = j % 66;
        const int y = by0 - 4 + r, xs = bx0 - 4 + 4 * c4;
        float4 v = make_float4(0.f, 0.f, 0.f, 0.f);
        if ((unsigned)y < 512u && (unsigned)xs < 512u)
            v = *(const float4*)((img ? Hb : Fb) + (size_t)y * 512 + xs);
        *(float4*)&stg[img][r][4 * c4] = v;
    }
    __syncthreads();

    // ---- loss: rows (by0+ty) and (by0+ty+4), 4 px each ----
    float vacc = 0.f;
    const size_t ks = (size_t)512 * 512;
#pragma unroll
    for (int rr = 0; rr < 2; ++rr) {
        const int y = by0 + ty + 4 * rr;
        const float* rwp = RW + (size_t)b * 25 * ks + (size_t)y * 512 + (bx0 + 4 * tx);
        float wsum[4] = {0.f,0.f,0.f,0.f}, fs[4] = {0.f,0.f,0.f,0.f}, hs[4] = {0.f,0.f,0.f,0.f};
#pragma unroll
        for (int di = 0; di < 5; ++di) {
            const int srow = ty + 4 * rr + di + 2;     // image row y+di-2
            float f12[12], h12[12];
            {
                const float4* pf = (const float4*)&stg[0][srow][4 * tx];
                const float4 a0 = pf[0], a1 = pf[1], a2 = pf[2];
                f12[0]=a0.x; f12[1]=a0.y; f12[2]=a0.z;  f12[3]=a0.w;
                f12[4]=a1.x; f12[5]=a1.y; f12[6]=a1.z;  f12[7]=a1.w;
                f12[8]=a2.x; f12[9]=a2.y; f12[10]=a2.z; f12[11]=a2.w;
                const float4* ph = (const float4*)&stg[1][srow][4 * tx];
                const float4 b0 = ph[0], b1 = ph[1], b2 = ph[2];
                h12[0]=b0.x; h12[1]=b0.y; h12[2]=b0.z;  h12[3]=b0.w;
                h12[4]=b1.x; h12[5]=b1.y; h12[6]=b1.z;  h12[7]=b1.w;
                h12[8]=b2.x; h12[9]=b2.y; h12[10]=b2.z; h12[11]=b2.w;
            }
#pragma unroll
            for (int dj = 0; dj < 5; ++dj) {
                const int k = di * 5 + dj;
                const float4 rv = *(const float4*)(rwp + (size_t)k * ks);
                const float w0 = swin[k] * rv.x, w1 = swin[k] * rv.y;
                const float w2 = swin[k] * rv.z, w3 = swin[k] * rv.w;
                wsum[0] += w0; wsum[1] += w1; wsum[2] += w2; wsum[3] += w3;
                fs[0] = fmaf(w0, f12[dj + 2], fs[0]);
                fs[1] = fmaf(w1, f12[dj + 3], fs[1]);
                fs[2] = fmaf(w2, f12[dj + 4], fs[2]);
                fs[3] = fmaf(w3, f12[dj + 5], fs[3]);
                hs[0] = fmaf(w0, h12[dj + 2], hs[0]);
                hs[1] = fmaf(w1, h12[dj + 3], hs[1]);
                hs[2] = fmaf(w2, h12[dj + 4], hs[2]);
                hs[3] = fmaf(w3, h12[dj + 5], hs[3]);
            }
        }
#pragma unroll
        for (int p = 0; p < 4; ++p) {
            const float d = (fs[p] - hs[p]) / wsum[p];
            vacc = fmaf(d, d, vacc);
        }
    }
#pragma unroll
    for (int off = 32; off > 0; off >>= 1) vacc += __shfl_down(vacc, off, 64);
    if ((tid & 63) == 0) wred[tid >> 6] = vacc;

    // ---- f1 build ----
    const float wt[4] = {WT0, WT1, WT1, WT0};
    for (int i = tid; i < 2 * 6 * 130; i += 256) {
        const int img = i / 780, j = i % 780;
        const int rr = j / 130, cc = j % 130;
        const int r1 = (by0 >> 1) - 1 + rr;
        const int c1 = (bx0 >> 1) - 1 + cc;
        int sy[4], sx[4];
#pragma unroll
        for (int k = 0; k < 4; ++k) {
            sy[k] = min(max(2 * r1 - 1 + k, 0), 511) - (by0 - 4);
            sx[k] = min(max(2 * c1 - 1 + k, 0), 511) - (bx0 - 4);
        }
        float a = 0.f;
#pragma unroll
        for (int ky = 0; ky < 4; ++ky) {
            const float* row = stg[img][sy[ky]];
            const float rs = WT0 * (row[sx[0]] + row[sx[3]])
                           + WT1 * (row[sx[1]] + row[sx[2]]);
            a = fmaf(wt[ky], rs, a);
        }
        f1b[img][rr][cc] = a;
        if (rr >= 1 && rr < 5 && cc >= 1 && cc < 129)
            (img ? h1 : f1)[(size_t)b * 65536 + (size_t)r1 * 256 + c1] = a;
    }
    __syncthreads();

    // ---- f2 build ----
    {
        const int img = tid >> 7, j = tid & 127;
        const int rr2 = j >> 6, cc2 = j & 63;
        const int y2 = (by0 >> 2) + rr2;
        const int x2 = (bx0 >> 2) + cc2;
        int fr[4], fc[4];
#pragma unroll
        for (int k = 0; k < 4; ++k) {
            fr[k] = min(max(2 * y2 - 1 + k, 0), 255) - ((by0 >> 1) - 1);
            fc[k] = min(max(2 * x2 - 1 + k, 0), 255) - ((bx0 >> 1) - 1);
        }
        float a = 0.f;
#pragma unroll
        for (int ky = 0; ky < 4; ++ky) {
            const float* row = f1b[img][fr[ky]];
            const float rs = WT0 * (row[fc[0]] + row[fc[3]])
                           + WT1 * (row[fc[1]] + row[fc[2]]);
            a = fmaf(wt[ky], rs, a);
        }
        (img ? h2 : f2)[(size_t)b * 16384 + (size_t)y2 * 128 + x2] = a;
    }

    if (tid == 0) {
        const float sB = wred[0] + wred[1] + wred[2] + wred[3];
        const unsigned lin = blockIdx.x + 2u * (blockIdx.y + 64u * blockIdx.z);
        slots[lin] = (double)sB * (double)(1.0f / (8.f * 512.f * 512.f));
    }
}

// ---------------------------------------------------------------------------
// K_B: tail in one launch (896 blocks). This round: staging vectorized in all
// three flavors (quad-aligned, origin -4, per-quad zero-pad predicate —
// legal because S % 4 == 0 so every 16B quad is fully in or out; level-3's
// column quads are always in-bounds, only rows clamp).
// ---------------------------------------------------------------------------
__global__ __launch_bounds__(256) void kb_kernel(
    const float* __restrict__ window,
    const float* __restrict__ rw1, const float* __restrict__ rw2,
    const float* __restrict__ rw3,
    const float* __restrict__ f1, const float* __restrict__ h1,
    const float* __restrict__ f2, const float* __restrict__ h2,
    double* __restrict__ slots)
{
    __shared__ __align__(16) float smem[5696]; // lvl1 2*2112 | lvl2 2*1088 | lvl3 5696
    __shared__ float swin[25];
    __shared__ float wred[4];

    const int tid = threadIdx.x;
    const int tx = tid & 63, ty = tid >> 6;
    if (tid < 25) swin[tid] = window[tid];
    const int lin = blockIdx.x;

    float v, scale;
    if (lin < 512) {
        // ---- level-1: S=256, tile 256x4, PX=4, float4 rw1; stage origin -4 ----
        constexpr int S = 256, LW = 264;
        const int b = lin >> 6, by0 = (lin & 63) * 4;
        float* sf = smem;
        float* sh = smem + 2112;
        const float* Fb = f1 + (size_t)b * S * S;
        const float* Hb = h1 + (size_t)b * S * S;
        // 66 quads x 8 rows x 2 imgs
        for (int i = tid; i < 2 * 8 * 66; i += 256) {
            const int img = i / 528, j = i % 528;
            const int r = j / 66, c4 = j % 66;
            const int y = by0 - 2 + r, xs = -4 + 4 * c4;
            float4 q = make_float4(0.f, 0.f, 0.f, 0.f);
            if ((unsigned)y < (unsigned)S && (unsigned)xs < (unsigned)S)
                q = *(const float4*)((img ? Hb : Fb) + (size_t)y * S + xs);
            *(float4*)&(img ? sh : sf)[r * LW + 4 * c4] = q;
        }
        __syncthreads();

        const size_t ks = (size_t)S * S;
        const float* rwp = rw1 + (size_t)b * 25 * ks + (size_t)(by0 + ty) * S + 4 * tx;
        float wsum[4] = {0.f,0.f,0.f,0.f}, fs[4] = {0.f,0.f,0.f,0.f}, hs[4] = {0.f,0.f,0.f,0.f};
#pragma unroll
        for (int di = 0; di < 5; ++di) {
            float f12[12], h12[12];
            const int ro = (ty + di) * LW + 4 * tx;
            {
                const float4 a0 = *(const float4*)&sf[ro], a1 = *(const float4*)&sf[ro + 4],
                             a2 = *(const float4*)&sf[ro + 8];
                f12[0]=a0.x; f12[1]=a0.y; f12[2]=a0.z;  f12[3]=a0.w;
                f12[4]=a1.x; f12[5]=a1.y; f12[6]=a1.z;  f12[7]=a1.w;
                f12[8]=a2.x; f12[9]=a2.y; f12[10]=a2.z; f12[11]=a2.w;
                const float4 b0 = *(const float4*)&sh[ro], b1 = *(const float4*)&sh[ro + 4],
                             b2 = *(const float4*)&sh[ro + 8];
                h12[0]=b0.x; h12[1]=b0.y; h12[2]=b0.z;  h12[3]=b0.w;
                h12[4]=b1.x; h12[5]=b1.y; h12[6]=b1.z;  h12[7]=b1.w;
                h12[8]=b2.x; h12[9]=b2.y; h12[10]=b2.z; h12[11]=b2.w;
            }
#pragma unroll
            for (int dj = 0; dj < 5; ++dj) {
                const int k = di * 5 + dj;
                const float4 rv = *(const float4*)(rwp + (size_t)k * ks);
                const float w0 = swin[k] * rv.x, w1 = swin[k] * rv.y;
                const float w2 = swin[k] * rv.z, w3 = swin[k] * rv.w;
                wsum[0] += w0; wsum[1] += w1; wsum[2] += w2; wsum[3] += w3;
                fs[0] = fmaf(w0, f12[dj + 2], fs[0]);
                fs[1] = fmaf(w1, f12[dj + 3], fs[1]);
                fs[2] = fmaf(w2, f12[dj + 4], fs[2]);
                fs[3] = fmaf(w3, f12[dj + 5], fs[3]);
                hs[0] = fmaf(w0, h12[dj + 2], hs[0]);
                hs[1] = fmaf(w1, h12[dj + 3], hs[1]);
                hs[2] = fmaf(w2, h12[dj + 4], hs[2]);
                hs[3] = fmaf(w3, h12[dj + 5], hs[3]);
            }
        }
        v = 0.f;
#pragma unroll
        for (int p = 0; p < 4; ++p) {
            const float d = (fs[p] - hs[p]) / wsum[p];
            v = fmaf(d, d, v);
        }
        scale = 0.5f / (8.f * 256.f * 256.f);
    } else if (lin < 768) {
        // ---- level-2: S=128, tile 128x4, PX=2, float2 rw2; stage origin -4 ----
        constexpr int S = 128, LW = 136;
        const int t = lin - 512;
        const int b = t >> 5, by0 = (t & 31) * 4;
        float* sf = smem;
        float* sh = smem + 1088;
        const float* Fb = f2 + (size_t)b * S * S;
        const float* Hb = h2 + (size_t)b * S * S;
        // 34 quads x 8 rows x 2 imgs
        for (int i = tid; i < 2 * 8 * 34; i += 256) {
            const int img = i / 272, j = i % 272;
            const int r = j / 34, c4 = j % 34;
            const int y = by0 - 2 + r, xs = -4 + 4 * c4;
            float4 q = make_float4(0.f, 0.f, 0.f, 0.f);
            if ((unsigned)y < (unsigned)S && (unsigned)xs < (unsigned)S)
                q = *(const float4*)((img ? Hb : Fb) + (size_t)y * S + xs);
            *(float4*)&(img ? sh : sf)[r * LW + 4 * c4] = q;
        }
        __syncthreads();

        const size_t ks = (size_t)S * S;
        const float* rwp = rw2 + (size_t)b * 25 * ks + (size_t)(by0 + ty) * S + 2 * tx;
        float wsum[2] = {0.f,0.f}, fs[2] = {0.f,0.f}, hs[2] = {0.f,0.f};
#pragma unroll
        for (int di = 0; di < 5; ++di) {
            // window col = 2tx+p+dj-2 -> stage idx 2tx+2+(p+dj), p+dj in [0,6]
            float f7[8], h7[8];
            const int ro = (ty + di) * LW + 2 * tx + 2;
#pragma unroll
            for (int q2 = 0; q2 < 4; ++q2) {
                const float2 af = *(const float2*)&sf[ro + 2 * q2];
                f7[2 * q2] = af.x; f7[2 * q2 + 1] = af.y;
                const float2 ah = *(const float2*)&sh[ro + 2 * q2];
                h7[2 * q2] = ah.x; h7[2 * q2 + 1] = ah.y;
            }
#pragma unroll
            for (int dj = 0; dj < 5; ++dj) {
                const int k = di * 5 + dj;
                const float2 rv = *(const float2*)(rwp + (size_t)k * ks);
                const float w0 = swin[k] * rv.x, w1 = swin[k] * rv.y;
                wsum[0] += w0; wsum[1] += w1;
                fs[0] = fmaf(w0, f7[dj + 0], fs[0]);
                fs[1] = fmaf(w1, f7[dj + 1], fs[1]);
                hs[0] = fmaf(w0, h7[dj + 0], hs[0]);
                hs[1] = fmaf(w1, h7[dj + 1], hs[1]);
            }
        }
        const float d0 = (fs[0] - hs[0]) / wsum[0];
        const float d1 = (fs[1] - hs[1]) / wsum[1];
        v = fmaf(d0, d0, d1 * d1);
        scale = 0.25f / (8.f * 128.f * 128.f);
    } else {
        // ---- level-3: S=64, rebuild L3 tile locally from f2/h2 ----
        const int t = lin - 768;
        const int b = t >> 4, by0 = (t & 15) * 4;
        float* p2 = smem;          // [2][18][128]
        float* l3 = smem + 4608;   // [2][8][68]
        const int fr0 = 2 * by0 - 5;
        // vector staging: cols always in-bounds (32 quads/row), rows clamp
        for (int i = tid; i < 2 * 18 * 32; i += 256) {
            const int img = i / 576, j = i % 576;
            const int r = j >> 5, c4 = j & 31;
            const int gy = min(max(fr0 + r, 0), 127);
            const float4 q = *(const float4*)((img ? h2 : f2)
                              + ((size_t)b * 128 + gy) * 128 + 4 * c4);
            *(float4*)&p2[img * 2304 + r * 128 + 4 * c4] = q;
        }
        __syncthreads();
        const float wt[4] = {WT0, WT1, WT1, WT0};
        for (int i = tid; i < 2 * 8 * 68; i += 256) {
            const int img = i / 544, j = i % 544;
            const int r = j / 68, c = j % 68;
            const int gy = by0 - 2 + r, gx = c - 2;
            float a = 0.f;
            if ((unsigned)gy < 64u && (unsigned)gx < 64u) {
                int ry[4], cx[4];
#pragma unroll
                for (int k = 0; k < 4; ++k) {
                    ry[k] = min(max(2 * gy - 1 + k, 0), 127) - fr0;
                    cx[k] = min(max(2 * gx - 1 + k, 0), 127);
                }
#pragma unroll
                for (int ky = 0; ky < 4; ++ky) {
                    const float* row = p2 + img * 2304 + ry[ky] * 128;
                    const float rs = WT0 * (row[cx[0]] + row[cx[3]])
                                   + WT1 * (row[cx[1]] + row[cx[2]]);
                    a = fmaf(wt[ky], rs, a);
                }
            }
            l3[i] = a;
        }
        __syncthreads();

        const size_t ks = 64 * 64;
        const float* rwp = rw3 + (size_t)b * 25 * ks + (size_t)(by0 + ty) * 64 + tx;
        float wsum = 0.f, fsv = 0.f, hsv = 0.f;
#pragma unroll
        for (int di = 0; di < 5; ++di) {
#pragma unroll
            for (int dj = 0; dj < 5; ++dj) {
                const int k = di * 5 + dj;
                const float wm = swin[k] * rwp[(size_t)k * ks];
                wsum += wm;
                fsv = fmaf(wm, l3[0 * 544 + (ty + di) * 68 + (tx + dj)], fsv);
                hsv = fmaf(wm, l3[1 * 544 + (ty + di) * 68 + (tx + dj)], hsv);
            }
        }
        const float d = (fsv - hsv) / wsum;
        v = d * d;
        scale = 0.125f / (8.f * 64.f * 64.f);
    }

#pragma unroll
    for (int off = 32; off > 0; off >>= 1) v += __shfl_down(v, off, 64);
    if ((tid & 63) == 0) wred[tid >> 6] = v;
    __syncthreads();
    if (tid == 0) {
        const float sB = wred[0] + wred[1] + wred[2] + wred[3];
        slots[lin] = (double)sB * (double)scale;
    }
}

__global__ void finalize_kernel(const double* __restrict__ slots, float* __restrict__ out, int n)
{
    __shared__ double dred[4];
    const int t = threadIdx.x;  // 256 threads
    double s = 0.0;
    for (int i = t; i < n; i += 256) s += slots[i];
#pragma unroll
    for (int off = 32; off > 0; off >>= 1) s += __shfl_down(s, off, 64);
    if ((t & 63) == 0) dred[t >> 6] = s;
    __syncthreads();
    if (t == 0) out[0] = (float)(dred[0] + dred[1] + dred[2] + dred[3]);
}

extern "C" void kernel_launch(void* const* d_in, const int* in_sizes, int n_in,
                              void* d_out, int out_size, void* d_ws, size_t ws_size,
                              hipStream_t stream)
{
    const float* fake   = (const float*)d_in[0];
    const float* hdr    = (const float*)d_in[1];
    const float* window = (const float*)d_in[2];
    const float* rw0    = (const float*)d_in[3];
    const float* rw1    = (const float*)d_in[4];
    const float* rw2    = (const float*)d_in[5];
    const float* rw3    = (const float*)d_in[6];
    float* out = (float*)d_out;

    const int B = 8;
    char* ws = (char*)d_ws;
    double* slots = (double*)ws;                 // 1920 doubles, all stored each call
    float* f1 = (float*)(ws + 32768);
    const size_t n1 = (size_t)B * 256 * 256;
    float* h1 = f1 + n1;
    float* f2 = h1 + n1;
    const size_t n2 = (size_t)B * 128 * 128;
    float* h2 = f2 + n2;

    // K1: level-0 loss + f1 + f2 build. 1024 blocks.
    k1_kernel<<<dim3(2, 64, B), 256, 0, stream>>>(
        fake, hdr, window, rw0, slots, f1, h1, f2, h2);

    // K_B: levels 1+2+3 in one launch (512+256+128 = 896 blocks).
    kb_kernel<<<dim3(896), 256, 0, stream>>>(
        window, rw1, rw2, rw3, f1, h1, f2, h2, slots + 1024);

    // finalize: 1920 slots.
    finalize_kernel<<<1, 256, 0, stream>>>(slots, out, 1920);
}